// Round 6
// baseline (362.882 us; speedup 1.0000x reference)
//
#include <hip/hip_runtime.h>

typedef __bf16 bf16;
typedef __attribute__((ext_vector_type(8))) __bf16 bf16x8;
typedef __attribute__((ext_vector_type(4))) __bf16 bf16x4;
typedef __attribute__((ext_vector_type(4))) float f32x4;

constexpr int T_SEQ = 2048;
constexpr int DIM   = 2048;
constexpr int NH    = 32;
constexpr int NKV   = 8;
constexpr int HD    = 64;
constexpr int QKV_N = DIM + 2 * NKV * HD;   // 3072
constexpr int MROWS = 2 * T_SEQ;            // 4096 (B*T)

// ---------------- cast f32 -> bf16 ----------------
__global__ void cast_kernel(const float* __restrict__ in, bf16* __restrict__ out, int n) {
  int stride = gridDim.x * blockDim.x * 4;
  for (int i = (blockIdx.x * blockDim.x + threadIdx.x) * 4; i < n; i += stride) {
    float4 v = *(const float4*)(in + i);
    bf16x4 o = { (bf16)v.x, (bf16)v.y, (bf16)v.z, (bf16)v.w };
    *(bf16x4*)(out + i) = o;
  }
}

// ---------------- GEMM: C[m][n] = sum_k A[m][k] * W[n][k] ----------------
template <typename OutT>
__global__ __launch_bounds__(256) void gemm_bt(const bf16* __restrict__ A,
                                               const bf16* __restrict__ W,
                                               OutT* __restrict__ C,
                                               int M, int N, int K) {
  constexpr int BM = 128, BN = 128, BK = 64;
  __shared__ __attribute__((aligned(16))) bf16 Ab[BM * BK];
  __shared__ __attribute__((aligned(16))) bf16 Bb[BN * BK];
  const int tid  = threadIdx.x;
  const int lane = tid & 63, wave = tid >> 6;
  const int bm = blockIdx.x * BM, bn = blockIdx.y * BN;
  const int wm = (wave >> 1) * 64, wn = (wave & 1) * 64;
  const int l15 = lane & 15, l4 = lane >> 4;

  f32x4 acc[4][4] = {};

  for (int k0 = 0; k0 < K; k0 += BK) {
    for (int i = 0; i < 4; ++i) {
      int chunk = i * 256 + tid;
      int r = chunk >> 3, c = (chunk & 7) << 3;
      __builtin_amdgcn_global_load_lds(
          (const __attribute__((address_space(1))) unsigned int*)(A + (size_t)(bm + r) * K + k0 + c),
          (__attribute__((address_space(3))) unsigned int*)(Ab + chunk * 8), 16, 0, 0);
      __builtin_amdgcn_global_load_lds(
          (const __attribute__((address_space(1))) unsigned int*)(W + (size_t)(bn + r) * K + k0 + c),
          (__attribute__((address_space(3))) unsigned int*)(Bb + chunk * 8), 16, 0, 0);
    }
    __syncthreads();
    #pragma unroll
    for (int kk = 0; kk < 2; ++kk) {
      const int co = kk * 32 + l4 * 8;
      bf16x8 af[4], bfr[4];
      #pragma unroll
      for (int mi = 0; mi < 4; ++mi)
        af[mi] = *(const bf16x8*)(Ab + (wm + mi * 16 + l15) * BK + co);
      #pragma unroll
      for (int ni = 0; ni < 4; ++ni)
        bfr[ni] = *(const bf16x8*)(Bb + (wn + ni * 16 + l15) * BK + co);
      #pragma unroll
      for (int mi = 0; mi < 4; ++mi)
        #pragma unroll
        for (int ni = 0; ni < 4; ++ni)
          acc[mi][ni] = __builtin_amdgcn_mfma_f32_16x16x32_bf16(af[mi], bfr[ni], acc[mi][ni], 0, 0, 0);
    }
    __syncthreads();
  }

  #pragma unroll
  for (int mi = 0; mi < 4; ++mi)
    #pragma unroll
    for (int ni = 0; ni < 4; ++ni) {
      size_t row = (size_t)bm + wm + mi * 16 + l4 * 4;
      int col = bn + wn + ni * 16 + l15;
      #pragma unroll
      for (int r = 0; r < 4; ++r)
        C[(row + r) * N + col] = (OutT)acc[mi][ni][r];
    }
}

// ---------------- RoPE, vectorized: 16 bf16 (8 pairs) per thread ----------------
__global__ void rope_kernel(bf16* __restrict__ qkv, const float* __restrict__ cs,
                            const float* __restrict__ sn) {
  int idx = blockIdx.x * blockDim.x + threadIdx.x;   // MROWS*160 total
  int m = idx / 160;
  int ch = idx - m * 160;
  int t = m & (T_SEQ - 1);
  int col, c;
  if (ch < 128) { int hh = ch >> 2; c = ch & 3; col = hh * 64 + c * 16; }
  else          { int ch2 = ch - 128; int hh = ch2 >> 2; c = ch2 & 3; col = DIM + hh * 64 + c * 16; }
  bf16* ptr = qkv + (size_t)m * QKV_N + col;
  bf16x8 v0 = *(bf16x8*)ptr, v1 = *(bf16x8*)(ptr + 8);
  const float* cp = cs + t * 32 + c * 8;
  const float* sp = sn + t * 32 + c * 8;
  float4 c0 = *(const float4*)cp, c1 = *(const float4*)(cp + 4);
  float4 s0 = *(const float4*)sp, s1 = *(const float4*)(sp + 4);
  float cc[8] = {c0.x, c0.y, c0.z, c0.w, c1.x, c1.y, c1.z, c1.w};
  float ss[8] = {s0.x, s0.y, s0.z, s0.w, s1.x, s1.y, s1.z, s1.w};
  bf16x8 o0, o1;
  #pragma unroll
  for (int j = 0; j < 4; ++j) {
    float a = (float)v0[2 * j], b = (float)v0[2 * j + 1];
    o0[2 * j]     = (bf16)(a * cc[j] - b * ss[j]);
    o0[2 * j + 1] = (bf16)(a * ss[j] + b * cc[j]);
  }
  #pragma unroll
  for (int j = 0; j < 4; ++j) {
    float a = (float)v1[2 * j], b = (float)v1[2 * j + 1];
    o1[2 * j]     = (bf16)(a * cc[4 + j] - b * ss[4 + j]);
    o1[2 * j + 1] = (bf16)(a * ss[4 + j] + b * cc[4 + j]);
  }
  *(bf16x8*)ptr = o0;
  *(bf16x8*)(ptr + 8) = o1;
}

// ---------------- Flash attention, causal GQA ----------------
// grid (8, NH, B); 8 waves (512 thr). Waves 0-3 own 128-row strip qpair,
// waves 4-7 own strip 15-qpair (32 q-rows per wave, 2 fragments of 16).
// Swapped QK^T AND swapped PV: lane owns q=l15 end-to-end, so softmax
// m/l/alpha are lane-local (no broadcasts). In-place softmax on z (no spills).
// Double-buffered K/V, one barrier per kv-tile.
__global__ __launch_bounds__(512, 4) void attn_kernel(const bf16* __restrict__ qkv,
                                                      bf16* __restrict__ y) {
  const int qpair = blockIdx.x, h = blockIdx.y, b = blockIdx.z;
  const int g = h >> 2;  // kv head
  const int tid = threadIdx.x, lane = tid & 63, wave = tid >> 6;
  const int l15 = lane & 15, l4 = lane >> 4;
  const int strip = (wave < 4) ? qpair : (15 - qpair);
  const int w4 = wave & 3;
  const int qbase = strip * 128 + w4 * 32;

  __shared__ __attribute__((aligned(16))) bf16 Kb[2][64 * 64];   // [kv][d], swizzled
  __shared__ __attribute__((aligned(16))) bf16 VTs[2][64 * 64];  // [d][kv], swizzled
  __shared__ __attribute__((aligned(16))) bf16 Pb[8][32 * 64];   // per-wave [q][kv], swizzled

  constexpr float SCALE2 = 0.125f * 1.44269504088896f;  // scale * log2(e)

  // Q fragments (B-operand of swapped QK^T): frag f rows qbase+f*16+l15
  bf16x8 qf[2][2];
  #pragma unroll
  for (int f = 0; f < 2; ++f) {
    const bf16* qp = qkv + ((size_t)b * T_SEQ + qbase + f * 16 + l15) * QKV_N + h * HD + l4 * 8;
    qf[f][0] = *(const bf16x8*)(qp);
    qf[f][1] = *(const bf16x8*)(qp + 32);
  }

  // oacc[f][dt] = O^T fragment: row d = dt*16 + l4*4 + r, col q = f*16 + l15
  f32x4 oacc[2][4] = {};
  float m_run[2] = {-INFINITY, -INFINITY}, l_run[2] = {0.f, 0.f};

  const int last_kt = (qbase + 31) >> 6;     // last tile this wave computes
  const int nt_loop = 32 - 2 * qpair;        // tiles staged (hi strip needs)
  const size_t kvbase = (size_t)b * T_SEQ;

  const int sr = tid >> 3, sc8 = (tid & 7) << 3;
  const int scsrc = sc8 ^ ((sr & 7) << 3);   // pre-swizzled K source col

  // ---- prologue: stage tile 0 into buffer 0 ----
  {
    __builtin_amdgcn_global_load_lds(
        (const __attribute__((address_space(1))) unsigned int*)
            (qkv + (kvbase + sr) * QKV_N + DIM + g * HD + scsrc),
        (__attribute__((address_space(3))) unsigned int*)(&Kb[0][0] + tid * 8), 16, 0, 0);
    const bf16* vp = qkv + (kvbase + wave * 8) * QKV_N + DIM + NKV * HD + g * HD + lane;
    bf16x8 vr;
    #pragma unroll
    for (int j = 0; j < 8; ++j) vr[j] = vp[(size_t)j * QKV_N];
    *(bf16x8*)((char*)&VTs[0][0] + ((lane * 128 + wave * 16) ^ ((lane & 7) << 4))) = vr;
    asm volatile("s_waitcnt vmcnt(0)" ::: "memory");
    __syncthreads();
  }

  int cur = 0;
  for (int kt = 0; kt < nt_loop; ++kt) {
    const bool has_next = (kt + 1) < nt_loop;
    bf16x8 vr;
    if (has_next) {
      __builtin_amdgcn_global_load_lds(
          (const __attribute__((address_space(1))) unsigned int*)
              (qkv + (kvbase + (kt + 1) * 64 + sr) * QKV_N + DIM + g * HD + scsrc),
          (__attribute__((address_space(3))) unsigned int*)(&Kb[cur ^ 1][0] + tid * 8), 16, 0, 0);
      const bf16* vp = qkv + (kvbase + (kt + 1) * 64 + wave * 8) * QKV_N
                           + DIM + NKV * HD + g * HD + lane;
      #pragma unroll
      for (int j = 0; j < 8; ++j) vr[j] = vp[(size_t)j * QKV_N];
    }

    if (kt <= last_kt) {
      const bf16* kb = &Kb[cur][0];
      const bf16* vt = &VTs[cur][0];

      // ---- S^T = K Q^T : z[f][nt], lane = (q=f*16+l15, k=nt*16+l4*4+r) ----
      f32x4 z[2][4];
      #pragma unroll
      for (int f = 0; f < 2; ++f)
        #pragma unroll
        for (int nt = 0; nt < 4; ++nt) z[f][nt] = (f32x4){0.f, 0.f, 0.f, 0.f};
      #pragma unroll
      for (int nt = 0; nt < 4; ++nt)
        #pragma unroll
        for (int kk = 0; kk < 2; ++kk) {
          bf16x8 kf = *(const bf16x8*)((const char*)kb +
              (((nt * 16 + l15) * 128 + (kk * 32 + l4 * 8) * 2) ^ ((l15 & 7) << 4)));
          z[0][nt] = __builtin_amdgcn_mfma_f32_16x16x32_bf16(kf, qf[0][kk], z[0][nt], 0, 0, 0);
          z[1][nt] = __builtin_amdgcn_mfma_f32_16x16x32_bf16(kf, qf[1][kk], z[1][nt], 0, 0, 0);
        }

      const bool domask = (kt == last_kt);
      bf16* pbw = &Pb[wave][0];

      #pragma unroll
      for (int f = 0; f < 2; ++f) {
        const int qg = qbase + f * 16 + l15;
        // in-place scale + mask
        #pragma unroll
        for (int nt = 0; nt < 4; ++nt)
          #pragma unroll
          for (int r = 0; r < 4; ++r) {
            float v = z[f][nt][r] * SCALE2;
            if (domask && (kt * 64 + nt * 16 + l4 * 4 + r > qg)) v = -INFINITY;
            z[f][nt][r] = v;
          }

        // row max: 15 in-register + 2 cross-group shfl (q=l15 lane-local)
        float vm = z[f][0][0];
        #pragma unroll
        for (int nt = 0; nt < 4; ++nt)
          #pragma unroll
          for (int r = 0; r < 4; ++r) vm = fmaxf(vm, z[f][nt][r]);
        vm = fmaxf(vm, __shfl_xor(vm, 16));
        vm = fmaxf(vm, __shfl_xor(vm, 32));
        float mnew = fmaxf(m_run[f], vm);
        float alpha = __builtin_amdgcn_exp2f(m_run[f] - mnew);
        m_run[f] = mnew;

        // P = exp2(z - m) in place; row sum
        float ps = 0.f;
        #pragma unroll
        for (int nt = 0; nt < 4; ++nt)
          #pragma unroll
          for (int r = 0; r < 4; ++r) {
            float pv = __builtin_amdgcn_exp2f(z[f][nt][r] - mnew);
            z[f][nt][r] = pv;
            ps += pv;
          }
        ps += __shfl_xor(ps, 16);
        ps += __shfl_xor(ps, 32);
        l_run[f] = l_run[f] * alpha + ps;

        // O^T rescale: col q=l15 matches this lane -> lane-local alpha
        #pragma unroll
        for (int dt = 0; dt < 4; ++dt)
          #pragma unroll
          for (int r = 0; r < 4; ++r) oacc[f][dt][r] *= alpha;

        // packed P write: row q=f*16+l15, 4 consecutive k -> b64
        const int row = f * 16 + l15;
        #pragma unroll
        for (int nt = 0; nt < 4; ++nt) {
          bf16x4 pk = { (bf16)z[f][nt][0], (bf16)z[f][nt][1],
                        (bf16)z[f][nt][2], (bf16)z[f][nt][3] };
          *(bf16x4*)((char*)pbw + ((row * 128 + nt * 32 + l4 * 8) ^ ((row & 7) << 4))) = pk;
        }
      }

      // ---- O^T += V^T P^T : mfma(A=V^T frag, B=P^T frag) ----
      #pragma unroll
      for (int kk = 0; kk < 2; ++kk) {
        bf16x8 pf0 = *(const bf16x8*)((const char*)pbw +
            ((l15 * 128 + kk * 64 + l4 * 16) ^ ((l15 & 7) << 4)));
        bf16x8 pf1 = *(const bf16x8*)((const char*)pbw +
            (((16 + l15) * 128 + kk * 64 + l4 * 16) ^ ((l15 & 7) << 4)));
        #pragma unroll
        for (int dt = 0; dt < 4; ++dt) {
          bf16x8 vf = *(const bf16x8*)((const char*)vt +
              (((dt * 16 + l15) * 128 + (kk * 32 + l4 * 8) * 2) ^ ((l15 & 7) << 4)));
          oacc[0][dt] = __builtin_amdgcn_mfma_f32_16x16x32_bf16(vf, pf0, oacc[0][dt], 0, 0, 0);
          oacc[1][dt] = __builtin_amdgcn_mfma_f32_16x16x32_bf16(vf, pf1, oacc[1][dt], 0, 0, 0);
        }
      }
    }

    if (has_next) {
      *(bf16x8*)((char*)&VTs[cur ^ 1][0] + ((lane * 128 + wave * 16) ^ ((lane & 7) << 4))) = vr;
      asm volatile("s_waitcnt vmcnt(0)" ::: "memory");
      __syncthreads();
      cur ^= 1;
    }
  }

  // ---- epilogue: O^T -> y. q = qbase+f*16+l15 (lane-local l), d = dt*16+l4*4+r ----
  #pragma unroll
  for (int f = 0; f < 2; ++f) {
    float linv = __builtin_amdgcn_rcpf(l_run[f]);
    bf16* yp = y + ((size_t)b * T_SEQ + qbase + f * 16 + l15) * DIM + h * HD + l4 * 4;
    #pragma unroll
    for (int dt = 0; dt < 4; ++dt) {
      bf16x4 ov = { (bf16)(oacc[f][dt][0] * linv), (bf16)(oacc[f][dt][1] * linv),
                    (bf16)(oacc[f][dt][2] * linv), (bf16)(oacc[f][dt][3] * linv) };
      *(bf16x4*)(yp + dt * 16) = ov;
    }
  }
}

// ---------------- launch ----------------
extern "C" void kernel_launch(void* const* d_in, const int* in_sizes, int n_in,
                              void* d_out, int out_size, void* d_ws, size_t ws_size,
                              hipStream_t stream) {
  const float* x    = (const float*)d_in[0];
  const float* cosb = (const float*)d_in[1];
  const float* sinb = (const float*)d_in[2];
  const float* wq   = (const float*)d_in[3];
  const float* wk   = (const float*)d_in[4];
  const float* wv   = (const float*)d_in[5];
  const float* wo   = (const float*)d_in[6];
  float* out = (float*)d_out;

  bf16* xb   = (bf16*)d_ws;                           // 4096*2048
  bf16* wqkv = xb + (size_t)MROWS * DIM;              // 3072*2048
  bf16* wob  = wqkv + (size_t)QKV_N * DIM;            // 2048*2048
  bf16* qkv  = wob + (size_t)DIM * DIM;               // 4096*3072
  bf16* y    = qkv + (size_t)MROWS * QKV_N;           // 4096*2048

  cast_kernel<<<2048, 256, 0, stream>>>(x, xb, MROWS * DIM);
  cast_kernel<<<2048, 256, 0, stream>>>(wq, wqkv, DIM * DIM);
  cast_kernel<<<512, 256, 0, stream>>>(wk, wqkv + (size_t)DIM * DIM, NKV * HD * DIM);
  cast_kernel<<<512, 256, 0, stream>>>(wv, wqkv + (size_t)(DIM + NKV * HD) * DIM, NKV * HD * DIM);
  cast_kernel<<<2048, 256, 0, stream>>>(wo, wob, DIM * DIM);

  // QKV projection: M=4096, N=3072, K=2048
  gemm_bt<bf16><<<dim3(MROWS / 128, QKV_N / 128), 256, 0, stream>>>(xb, wqkv, qkv, MROWS, QKV_N, DIM);

  // RoPE on q,k
  rope_kernel<<<(MROWS * 160) / 256, 256, 0, stream>>>(qkv, cosb, sinb);

  // attention: balanced 128-row strip pairs, 32 q-rows/wave
  attn_kernel<<<dim3(8, NH, 2), 512, 0, stream>>>(qkv, y);

  // output projection: M=4096, N=2048, K=2048, f32 out
  gemm_bt<float><<<dim3(MROWS / 128, DIM / 128), 256, 0, stream>>>(y, wob, out, MROWS, DIM, DIM);
}

// Round 7
// 328.065 us; speedup vs baseline: 1.1061x; 1.1061x over previous
//
#include <hip/hip_runtime.h>

typedef __bf16 bf16;
typedef __attribute__((ext_vector_type(8))) __bf16 bf16x8;
typedef __attribute__((ext_vector_type(4))) __bf16 bf16x4;
typedef __attribute__((ext_vector_type(4))) float f32x4;

constexpr int T_SEQ = 2048;
constexpr int DIM   = 2048;
constexpr int NH    = 32;
constexpr int NKV   = 8;
constexpr int HD    = 64;
constexpr int QKV_N = DIM + 2 * NKV * HD;   // 3072
constexpr int MROWS = 2 * T_SEQ;            // 4096 (B*T)

// ---------------- cast f32 -> bf16 ----------------
__global__ void cast_kernel(const float* __restrict__ in, bf16* __restrict__ out, int n) {
  int stride = gridDim.x * blockDim.x * 4;
  for (int i = (blockIdx.x * blockDim.x + threadIdx.x) * 4; i < n; i += stride) {
    float4 v = *(const float4*)(in + i);
    bf16x4 o = { (bf16)v.x, (bf16)v.y, (bf16)v.z, (bf16)v.w };
    *(bf16x4*)(out + i) = o;
  }
}

// ---------------- GEMM: C[m][n] = sum_k A[m][k] * W[n][k] ----------------
// 1-D grid, XCD-aware swizzle: chunk of nwg/8 consecutive blocks per XCD
// shares W-panels in that XCD's private L2. M/128 must be 32 (bitops below).
template <typename OutT>
__global__ __launch_bounds__(256) void gemm_bt(const bf16* __restrict__ A,
                                               const bf16* __restrict__ W,
                                               OutT* __restrict__ C,
                                               int M, int N, int K, int cpx) {
  constexpr int BM = 128, BN = 128, BK = 64;
  __shared__ __attribute__((aligned(16))) bf16 Ab[BM * BK];
  __shared__ __attribute__((aligned(16))) bf16 Bb[BN * BK];
  const int tid  = threadIdx.x;
  const int lane = tid & 63, wave = tid >> 6;
  const int orig = blockIdx.x;
  const int wg = (orig & 7) * cpx + (orig >> 3);   // bijective: nwg % 8 == 0
  const int bm = (wg & 31) * BM, bn = (wg >> 5) * BN;
  const int wm = (wave >> 1) * 64, wn = (wave & 1) * 64;
  const int l15 = lane & 15, l4 = lane >> 4;

  f32x4 acc[4][4] = {};

  for (int k0 = 0; k0 < K; k0 += BK) {
    for (int i = 0; i < 4; ++i) {
      int chunk = i * 256 + tid;
      int r = chunk >> 3, c = (chunk & 7) << 3;
      __builtin_amdgcn_global_load_lds(
          (const __attribute__((address_space(1))) unsigned int*)(A + (size_t)(bm + r) * K + k0 + c),
          (__attribute__((address_space(3))) unsigned int*)(Ab + chunk * 8), 16, 0, 0);
      __builtin_amdgcn_global_load_lds(
          (const __attribute__((address_space(1))) unsigned int*)(W + (size_t)(bn + r) * K + k0 + c),
          (__attribute__((address_space(3))) unsigned int*)(Bb + chunk * 8), 16, 0, 0);
    }
    __syncthreads();
    #pragma unroll
    for (int kk = 0; kk < 2; ++kk) {
      const int co = kk * 32 + l4 * 8;
      bf16x8 af[4], bfr[4];
      #pragma unroll
      for (int mi = 0; mi < 4; ++mi)
        af[mi] = *(const bf16x8*)(Ab + (wm + mi * 16 + l15) * BK + co);
      #pragma unroll
      for (int ni = 0; ni < 4; ++ni)
        bfr[ni] = *(const bf16x8*)(Bb + (wn + ni * 16 + l15) * BK + co);
      #pragma unroll
      for (int mi = 0; mi < 4; ++mi)
        #pragma unroll
        for (int ni = 0; ni < 4; ++ni)
          acc[mi][ni] = __builtin_amdgcn_mfma_f32_16x16x32_bf16(af[mi], bfr[ni], acc[mi][ni], 0, 0, 0);
    }
    __syncthreads();
  }

  #pragma unroll
  for (int mi = 0; mi < 4; ++mi)
    #pragma unroll
    for (int ni = 0; ni < 4; ++ni) {
      size_t row = (size_t)bm + wm + mi * 16 + l4 * 4;
      int col = bn + wn + ni * 16 + l15;
      #pragma unroll
      for (int r = 0; r < 4; ++r)
        C[(row + r) * N + col] = (OutT)acc[mi][ni][r];
    }
}

// ---------------- RoPE, vectorized: 16 bf16 (8 pairs) per thread ----------------
__global__ void rope_kernel(bf16* __restrict__ qkv, const float* __restrict__ cs,
                            const float* __restrict__ sn) {
  int idx = blockIdx.x * blockDim.x + threadIdx.x;   // MROWS*160 total
  int m = idx / 160;
  int ch = idx - m * 160;
  int t = m & (T_SEQ - 1);
  int col, c;
  if (ch < 128) { int hh = ch >> 2; c = ch & 3; col = hh * 64 + c * 16; }
  else          { int ch2 = ch - 128; int hh = ch2 >> 2; c = ch2 & 3; col = DIM + hh * 64 + c * 16; }
  bf16* ptr = qkv + (size_t)m * QKV_N + col;
  bf16x8 v0 = *(bf16x8*)ptr, v1 = *(bf16x8*)(ptr + 8);
  const float* cp = cs + t * 32 + c * 8;
  const float* sp = sn + t * 32 + c * 8;
  float4 c0 = *(const float4*)cp, c1 = *(const float4*)(cp + 4);
  float4 s0 = *(const float4*)sp, s1 = *(const float4*)(sp + 4);
  float cc[8] = {c0.x, c0.y, c0.z, c0.w, c1.x, c1.y, c1.z, c1.w};
  float ss[8] = {s0.x, s0.y, s0.z, s0.w, s1.x, s1.y, s1.z, s1.w};
  bf16x8 o0, o1;
  #pragma unroll
  for (int j = 0; j < 4; ++j) {
    float a = (float)v0[2 * j], b = (float)v0[2 * j + 1];
    o0[2 * j]     = (bf16)(a * cc[j] - b * ss[j]);
    o0[2 * j + 1] = (bf16)(a * ss[j] + b * cc[j]);
  }
  #pragma unroll
  for (int j = 0; j < 4; ++j) {
    float a = (float)v1[2 * j], b = (float)v1[2 * j + 1];
    o1[2 * j]     = (bf16)(a * cc[4 + j] - b * ss[4 + j]);
    o1[2 * j + 1] = (bf16)(a * ss[4 + j] + b * cc[4 + j]);
  }
  *(bf16x8*)ptr = o0;
  *(bf16x8*)(ptr + 8) = o1;
}

// ---------------- Flash attention, causal GQA ----------------
// grid (8, NH, B); 8 waves (512 thr). Waves 0-3 own 128-row strip qpair,
// waves 4-7 own strip 15-qpair (32 q-rows per wave, 2 fragments of 16).
// Swapped QK^T AND swapped PV: lane owns q=l15 end-to-end, so softmax
// m/l/alpha are lane-local (no broadcasts). In-place softmax on z.
// __launch_bounds__(512,2): 2 blocks/CU -> 128-VGPR cap, NO scratch spill.
__global__ __launch_bounds__(512, 2) void attn_kernel(const bf16* __restrict__ qkv,
                                                      bf16* __restrict__ y) {
  const int qpair = blockIdx.x, h = blockIdx.y, b = blockIdx.z;
  const int g = h >> 2;  // kv head
  const int tid = threadIdx.x, lane = tid & 63, wave = tid >> 6;
  const int l15 = lane & 15, l4 = lane >> 4;
  const int strip = (wave < 4) ? qpair : (15 - qpair);
  const int w4 = wave & 3;
  const int qbase = strip * 128 + w4 * 32;

  __shared__ __attribute__((aligned(16))) bf16 Kb[2][64 * 64];   // [kv][d], swizzled
  __shared__ __attribute__((aligned(16))) bf16 VTs[2][64 * 64];  // [d][kv], swizzled
  __shared__ __attribute__((aligned(16))) bf16 Pb[8][32 * 64];   // per-wave [q][kv], swizzled

  constexpr float SCALE2 = 0.125f * 1.44269504088896f;  // scale * log2(e)

  // Q fragments (B-operand of swapped QK^T): frag f rows qbase+f*16+l15
  bf16x8 qf[2][2];
  #pragma unroll
  for (int f = 0; f < 2; ++f) {
    const bf16* qp = qkv + ((size_t)b * T_SEQ + qbase + f * 16 + l15) * QKV_N + h * HD + l4 * 8;
    qf[f][0] = *(const bf16x8*)(qp);
    qf[f][1] = *(const bf16x8*)(qp + 32);
  }

  // oacc[f][dt] = O^T fragment: row d = dt*16 + l4*4 + r, col q = f*16 + l15
  f32x4 oacc[2][4] = {};
  float m_run[2] = {-INFINITY, -INFINITY}, l_run[2] = {0.f, 0.f};

  const int last_kt = (qbase + 31) >> 6;     // last tile this wave computes
  const int nt_loop = 32 - 2 * qpair;        // tiles staged (hi strip needs)
  const size_t kvbase = (size_t)b * T_SEQ;

  const int sr = tid >> 3, sc8 = (tid & 7) << 3;
  const int scsrc = sc8 ^ ((sr & 7) << 3);   // pre-swizzled K source col

  // ---- prologue: stage tile 0 into buffer 0 ----
  {
    __builtin_amdgcn_global_load_lds(
        (const __attribute__((address_space(1))) unsigned int*)
            (qkv + (kvbase + sr) * QKV_N + DIM + g * HD + scsrc),
        (__attribute__((address_space(3))) unsigned int*)(&Kb[0][0] + tid * 8), 16, 0, 0);
    const bf16* vp = qkv + (kvbase + wave * 8) * QKV_N + DIM + NKV * HD + g * HD + lane;
    bf16x8 vr;
    #pragma unroll
    for (int j = 0; j < 8; ++j) vr[j] = vp[(size_t)j * QKV_N];
    *(bf16x8*)((char*)&VTs[0][0] + ((lane * 128 + wave * 16) ^ ((lane & 7) << 4))) = vr;
    asm volatile("s_waitcnt vmcnt(0)" ::: "memory");
    __syncthreads();
  }

  int cur = 0;
  for (int kt = 0; kt < nt_loop; ++kt) {
    const bool has_next = (kt + 1) < nt_loop;
    bf16x8 vr;
    if (has_next) {
      __builtin_amdgcn_global_load_lds(
          (const __attribute__((address_space(1))) unsigned int*)
              (qkv + (kvbase + (kt + 1) * 64 + sr) * QKV_N + DIM + g * HD + scsrc),
          (__attribute__((address_space(3))) unsigned int*)(&Kb[cur ^ 1][0] + tid * 8), 16, 0, 0);
      const bf16* vp = qkv + (kvbase + (kt + 1) * 64 + wave * 8) * QKV_N
                           + DIM + NKV * HD + g * HD + lane;
      #pragma unroll
      for (int j = 0; j < 8; ++j) vr[j] = vp[(size_t)j * QKV_N];
    }

    if (kt <= last_kt) {
      const bf16* kb = &Kb[cur][0];
      const bf16* vt = &VTs[cur][0];

      // ---- S^T = K Q^T : z[f][nt], lane = (q=f*16+l15, k=nt*16+l4*4+r) ----
      f32x4 z[2][4];
      #pragma unroll
      for (int f = 0; f < 2; ++f)
        #pragma unroll
        for (int nt = 0; nt < 4; ++nt) z[f][nt] = (f32x4){0.f, 0.f, 0.f, 0.f};
      #pragma unroll
      for (int nt = 0; nt < 4; ++nt)
        #pragma unroll
        for (int kk = 0; kk < 2; ++kk) {
          bf16x8 kf = *(const bf16x8*)((const char*)kb +
              (((nt * 16 + l15) * 128 + (kk * 32 + l4 * 8) * 2) ^ ((l15 & 7) << 4)));
          z[0][nt] = __builtin_amdgcn_mfma_f32_16x16x32_bf16(kf, qf[0][kk], z[0][nt], 0, 0, 0);
          z[1][nt] = __builtin_amdgcn_mfma_f32_16x16x32_bf16(kf, qf[1][kk], z[1][nt], 0, 0, 0);
        }

      const bool domask = (kt == last_kt);
      bf16* pbw = &Pb[wave][0];

      #pragma unroll
      for (int f = 0; f < 2; ++f) {
        const int qg = qbase + f * 16 + l15;
        // in-place scale + mask
        #pragma unroll
        for (int nt = 0; nt < 4; ++nt)
          #pragma unroll
          for (int r = 0; r < 4; ++r) {
            float v = z[f][nt][r] * SCALE2;
            if (domask && (kt * 64 + nt * 16 + l4 * 4 + r > qg)) v = -INFINITY;
            z[f][nt][r] = v;
          }

        // row max: 15 in-register + 2 cross-group shfl (q=l15 lane-local)
        float vm = z[f][0][0];
        #pragma unroll
        for (int nt = 0; nt < 4; ++nt)
          #pragma unroll
          for (int r = 0; r < 4; ++r) vm = fmaxf(vm, z[f][nt][r]);
        vm = fmaxf(vm, __shfl_xor(vm, 16));
        vm = fmaxf(vm, __shfl_xor(vm, 32));
        float mnew = fmaxf(m_run[f], vm);
        float alpha = __builtin_amdgcn_exp2f(m_run[f] - mnew);
        m_run[f] = mnew;

        // P = exp2(z - m) in place; row sum
        float ps = 0.f;
        #pragma unroll
        for (int nt = 0; nt < 4; ++nt)
          #pragma unroll
          for (int r = 0; r < 4; ++r) {
            float pv = __builtin_amdgcn_exp2f(z[f][nt][r] - mnew);
            z[f][nt][r] = pv;
            ps += pv;
          }
        ps += __shfl_xor(ps, 16);
        ps += __shfl_xor(ps, 32);
        l_run[f] = l_run[f] * alpha + ps;

        // O^T rescale: col q=l15 matches this lane -> lane-local alpha
        #pragma unroll
        for (int dt = 0; dt < 4; ++dt)
          #pragma unroll
          for (int r = 0; r < 4; ++r) oacc[f][dt][r] *= alpha;

        // packed P write: row q=f*16+l15, 4 consecutive k -> b64
        const int row = f * 16 + l15;
        #pragma unroll
        for (int nt = 0; nt < 4; ++nt) {
          bf16x4 pk = { (bf16)z[f][nt][0], (bf16)z[f][nt][1],
                        (bf16)z[f][nt][2], (bf16)z[f][nt][3] };
          *(bf16x4*)((char*)pbw + ((row * 128 + nt * 32 + l4 * 8) ^ ((row & 7) << 4))) = pk;
        }
      }

      // ---- O^T += V^T P^T : mfma(A=V^T frag, B=P^T frag) ----
      #pragma unroll
      for (int kk = 0; kk < 2; ++kk) {
        bf16x8 pf0 = *(const bf16x8*)((const char*)pbw +
            ((l15 * 128 + kk * 64 + l4 * 16) ^ ((l15 & 7) << 4)));
        bf16x8 pf1 = *(const bf16x8*)((const char*)pbw +
            (((16 + l15) * 128 + kk * 64 + l4 * 16) ^ ((l15 & 7) << 4)));
        #pragma unroll
        for (int dt = 0; dt < 4; ++dt) {
          bf16x8 vf = *(const bf16x8*)((const char*)vt +
              (((dt * 16 + l15) * 128 + (kk * 32 + l4 * 8) * 2) ^ ((l15 & 7) << 4)));
          oacc[0][dt] = __builtin_amdgcn_mfma_f32_16x16x32_bf16(vf, pf0, oacc[0][dt], 0, 0, 0);
          oacc[1][dt] = __builtin_amdgcn_mfma_f32_16x16x32_bf16(vf, pf1, oacc[1][dt], 0, 0, 0);
        }
      }
    }

    if (has_next) {
      *(bf16x8*)((char*)&VTs[cur ^ 1][0] + ((lane * 128 + wave * 16) ^ ((lane & 7) << 4))) = vr;
      asm volatile("s_waitcnt vmcnt(0)" ::: "memory");
      __syncthreads();
      cur ^= 1;
    }
  }

  // ---- epilogue: O^T -> y. q = qbase+f*16+l15 (lane-local l), d = dt*16+l4*4+r ----
  #pragma unroll
  for (int f = 0; f < 2; ++f) {
    float linv = __builtin_amdgcn_rcpf(l_run[f]);
    bf16* yp = y + ((size_t)b * T_SEQ + qbase + f * 16 + l15) * DIM + h * HD + l4 * 4;
    #pragma unroll
    for (int dt = 0; dt < 4; ++dt) {
      bf16x4 ov = { (bf16)(oacc[f][dt][0] * linv), (bf16)(oacc[f][dt][1] * linv),
                    (bf16)(oacc[f][dt][2] * linv), (bf16)(oacc[f][dt][3] * linv) };
      *(bf16x4*)(yp + dt * 16) = ov;
    }
  }
}

// ---------------- launch ----------------
extern "C" void kernel_launch(void* const* d_in, const int* in_sizes, int n_in,
                              void* d_out, int out_size, void* d_ws, size_t ws_size,
                              hipStream_t stream) {
  const float* x    = (const float*)d_in[0];
  const float* cosb = (const float*)d_in[1];
  const float* sinb = (const float*)d_in[2];
  const float* wq   = (const float*)d_in[3];
  const float* wk   = (const float*)d_in[4];
  const float* wv   = (const float*)d_in[5];
  const float* wo   = (const float*)d_in[6];
  float* out = (float*)d_out;

  bf16* xb   = (bf16*)d_ws;                           // 4096*2048
  bf16* wqkv = xb + (size_t)MROWS * DIM;              // 3072*2048
  bf16* wob  = wqkv + (size_t)QKV_N * DIM;            // 2048*2048
  bf16* qkv  = wob + (size_t)DIM * DIM;               // 4096*3072
  bf16* y    = qkv + (size_t)MROWS * QKV_N;           // 4096*2048

  cast_kernel<<<2048, 256, 0, stream>>>(x, xb, MROWS * DIM);
  cast_kernel<<<2048, 256, 0, stream>>>(wq, wqkv, DIM * DIM);
  cast_kernel<<<512, 256, 0, stream>>>(wk, wqkv + (size_t)DIM * DIM, NKV * HD * DIM);
  cast_kernel<<<512, 256, 0, stream>>>(wv, wqkv + (size_t)(DIM + NKV * HD) * DIM, NKV * HD * DIM);
  cast_kernel<<<2048, 256, 0, stream>>>(wo, wob, DIM * DIM);

  // QKV projection: M=4096, N=3072, K=2048 (768 blocks, XCD-swizzled)
  gemm_bt<bf16><<<768, 256, 0, stream>>>(xb, wqkv, qkv, MROWS, QKV_N, DIM, 768 / 8);

  // RoPE on q,k
  rope_kernel<<<(MROWS * 160) / 256, 256, 0, stream>>>(qkv, cosb, sinb);

  // attention: balanced 128-row strip pairs, 32 q-rows/wave
  attn_kernel<<<dim3(8, NH, 2), 512, 0, stream>>>(qkv, y);

  // output projection: M=4096, N=2048, K=2048 (512 blocks, XCD-swizzled)
  gemm_bt<float><<<512, 256, 0, stream>>>(y, wob, out, MROWS, DIM, DIM, 512 / 8);
}

// Round 8
// 272.042 us; speedup vs baseline: 1.3339x; 1.2059x over previous
//
#include <hip/hip_runtime.h>

typedef __bf16 bf16;
typedef __attribute__((ext_vector_type(8))) __bf16 bf16x8;
typedef __attribute__((ext_vector_type(4))) __bf16 bf16x4;
typedef __attribute__((ext_vector_type(4))) float f32x4;

constexpr int T_SEQ = 2048;
constexpr int DIM   = 2048;
constexpr int NH    = 32;
constexpr int NKV   = 8;
constexpr int HD    = 64;
constexpr int QKV_N = DIM + 2 * NKV * HD;   // 3072
constexpr int MROWS = 2 * T_SEQ;            // 4096 (B*T)

// ---------------- cast f32 -> bf16 ----------------
__global__ void cast_kernel(const float* __restrict__ in, bf16* __restrict__ out, int n) {
  int stride = gridDim.x * blockDim.x * 4;
  for (int i = (blockIdx.x * blockDim.x + threadIdx.x) * 4; i < n; i += stride) {
    float4 v = *(const float4*)(in + i);
    bf16x4 o = { (bf16)v.x, (bf16)v.y, (bf16)v.z, (bf16)v.w };
    *(bf16x4*)(out + i) = o;
  }
}

// ---------------- GEMM: C[m][n] = sum_k A[m][k] * W[n][k] ----------------
// 1-D grid, XCD-aware swizzle. M/128 must be 32 (bitops below).
template <typename OutT>
__global__ __launch_bounds__(256) void gemm_bt(const bf16* __restrict__ A,
                                               const bf16* __restrict__ W,
                                               OutT* __restrict__ C,
                                               int M, int N, int K, int cpx) {
  constexpr int BM = 128, BN = 128, BK = 64;
  __shared__ __attribute__((aligned(16))) bf16 Ab[BM * BK];
  __shared__ __attribute__((aligned(16))) bf16 Bb[BN * BK];
  const int tid  = threadIdx.x;
  const int lane = tid & 63, wave = tid >> 6;
  const int orig = blockIdx.x;
  const int wg = (orig & 7) * cpx + (orig >> 3);   // bijective: nwg % 8 == 0
  const int bm = (wg & 31) * BM, bn = (wg >> 5) * BN;
  const int wm = (wave >> 1) * 64, wn = (wave & 1) * 64;
  const int l15 = lane & 15, l4 = lane >> 4;

  f32x4 acc[4][4] = {};

  for (int k0 = 0; k0 < K; k0 += BK) {
    for (int i = 0; i < 4; ++i) {
      int chunk = i * 256 + tid;
      int r = chunk >> 3, c = (chunk & 7) << 3;
      __builtin_amdgcn_global_load_lds(
          (const __attribute__((address_space(1))) unsigned int*)(A + (size_t)(bm + r) * K + k0 + c),
          (__attribute__((address_space(3))) unsigned int*)(Ab + chunk * 8), 16, 0, 0);
      __builtin_amdgcn_global_load_lds(
          (const __attribute__((address_space(1))) unsigned int*)(W + (size_t)(bn + r) * K + k0 + c),
          (__attribute__((address_space(3))) unsigned int*)(Bb + chunk * 8), 16, 0, 0);
    }
    __syncthreads();
    #pragma unroll
    for (int kk = 0; kk < 2; ++kk) {
      const int co = kk * 32 + l4 * 8;
      bf16x8 af[4], bfr[4];
      #pragma unroll
      for (int mi = 0; mi < 4; ++mi)
        af[mi] = *(const bf16x8*)(Ab + (wm + mi * 16 + l15) * BK + co);
      #pragma unroll
      for (int ni = 0; ni < 4; ++ni)
        bfr[ni] = *(const bf16x8*)(Bb + (wn + ni * 16 + l15) * BK + co);
      #pragma unroll
      for (int mi = 0; mi < 4; ++mi)
        #pragma unroll
        for (int ni = 0; ni < 4; ++ni)
          acc[mi][ni] = __builtin_amdgcn_mfma_f32_16x16x32_bf16(af[mi], bfr[ni], acc[mi][ni], 0, 0, 0);
    }
    __syncthreads();
  }

  #pragma unroll
  for (int mi = 0; mi < 4; ++mi)
    #pragma unroll
    for (int ni = 0; ni < 4; ++ni) {
      size_t row = (size_t)bm + wm + mi * 16 + l4 * 4;
      int col = bn + wn + ni * 16 + l15;
      #pragma unroll
      for (int r = 0; r < 4; ++r)
        C[(row + r) * N + col] = (OutT)acc[mi][ni][r];
    }
}

// ---------------- RoPE, vectorized: 16 bf16 (8 pairs) per thread ----------------
__global__ void rope_kernel(bf16* __restrict__ qkv, const float* __restrict__ cs,
                            const float* __restrict__ sn) {
  int idx = blockIdx.x * blockDim.x + threadIdx.x;   // MROWS*160 total
  int m = idx / 160;
  int ch = idx - m * 160;
  int t = m & (T_SEQ - 1);
  int col, c;
  if (ch < 128) { int hh = ch >> 2; c = ch & 3; col = hh * 64 + c * 16; }
  else          { int ch2 = ch - 128; int hh = ch2 >> 2; c = ch2 & 3; col = DIM + hh * 64 + c * 16; }
  bf16* ptr = qkv + (size_t)m * QKV_N + col;
  bf16x8 v0 = *(bf16x8*)ptr, v1 = *(bf16x8*)(ptr + 8);
  const float* cp = cs + t * 32 + c * 8;
  const float* sp = sn + t * 32 + c * 8;
  float4 c0 = *(const float4*)cp, c1 = *(const float4*)(cp + 4);
  float4 s0 = *(const float4*)sp, s1 = *(const float4*)(sp + 4);
  float cc[8] = {c0.x, c0.y, c0.z, c0.w, c1.x, c1.y, c1.z, c1.w};
  float ss[8] = {s0.x, s0.y, s0.z, s0.w, s1.x, s1.y, s1.z, s1.w};
  bf16x8 o0, o1;
  #pragma unroll
  for (int j = 0; j < 4; ++j) {
    float a = (float)v0[2 * j], b = (float)v0[2 * j + 1];
    o0[2 * j]     = (bf16)(a * cc[j] - b * ss[j]);
    o0[2 * j + 1] = (bf16)(a * ss[j] + b * cc[j]);
  }
  #pragma unroll
  for (int j = 0; j < 4; ++j) {
    float a = (float)v1[2 * j], b = (float)v1[2 * j + 1];
    o1[2 * j]     = (bf16)(a * cc[4 + j] - b * ss[4 + j]);
    o1[2 * j + 1] = (bf16)(a * ss[4 + j] + b * cc[4 + j]);
  }
  *(bf16x8*)ptr = o0;
  *(bf16x8*)(ptr + 8) = o1;
}

// ---------------- Flash attention, causal GQA ----------------
// grid (NH, 16, B); 256 thr = 4 waves x 32 q-rows = ONE 128-row strip/block.
// strip = 15 - blockIdx.y (longest blocks dispatch first -> LPT balance).
// No idle waves; 48 KB LDS -> 3 blocks/CU, independent barrier domains.
// Swapped QK^T and PV: lane owns q=l15 end-to-end (lane-local softmax).
// Double-buffered K (global_load_lds) + V (reg-gather), 1 barrier/tile.
__global__ __launch_bounds__(256, 3) void attn_kernel(const bf16* __restrict__ qkv,
                                                      bf16* __restrict__ y) {
  const int h = blockIdx.x, b = blockIdx.z;
  const int strip = 15 - blockIdx.y;
  const int g = h >> 2;  // kv head
  const int tid = threadIdx.x, lane = tid & 63, wave = tid >> 6;
  const int l15 = lane & 15, l4 = lane >> 4;
  const int qbase = strip * 128 + wave * 32;

  __shared__ __attribute__((aligned(16))) bf16 Kb[2][64 * 64];   // [kv][d], swizzled
  __shared__ __attribute__((aligned(16))) bf16 VTs[2][64 * 64];  // [d][kv], swizzled
  __shared__ __attribute__((aligned(16))) bf16 Pb[4][32 * 64];   // per-wave [q][kv], swizzled

  constexpr float SCALE2 = 0.125f * 1.44269504088896f;  // scale * log2(e)

  // Q fragments (B-operand of swapped QK^T): frag f rows qbase+f*16+l15
  bf16x8 qf[2][2];
  #pragma unroll
  for (int f = 0; f < 2; ++f) {
    const bf16* qp = qkv + ((size_t)b * T_SEQ + qbase + f * 16 + l15) * QKV_N + h * HD + l4 * 8;
    qf[f][0] = *(const bf16x8*)(qp);
    qf[f][1] = *(const bf16x8*)(qp + 32);
  }

  // oacc[f][dt] = O^T fragment: row d = dt*16 + l4*4 + r, col q = f*16 + l15
  f32x4 oacc[2][4] = {};
  float m_run[2] = {-INFINITY, -INFINITY}, l_run[2] = {0.f, 0.f};

  const int last_kt = (qbase + 31) >> 6;     // this wave's diagonal tile
  const int nt_loop = 2 * strip + 2;         // tiles staged for the strip
  const size_t kvbase = (size_t)b * T_SEQ;

  const int sr = tid >> 3, sc8 = (tid & 7) << 3;
  const int scsrc = sc8 ^ ((sr & 7) << 3);   // pre-swizzled K source col (bf16 units)

  // ---- prologue: stage tile 0 into buffer 0 ----
  {
    #pragma unroll
    for (int i = 0; i < 2; ++i) {
      int chunk = i * 256 + tid;
      int r = chunk >> 3;
      int csrc = ((chunk & 7) << 3) ^ ((r & 7) << 3);
      __builtin_amdgcn_global_load_lds(
          (const __attribute__((address_space(1))) unsigned int*)
              (qkv + (kvbase + r) * QKV_N + DIM + g * HD + csrc),
          (__attribute__((address_space(3))) unsigned int*)(&Kb[0][0] + chunk * 8), 16, 0, 0);
    }
    const bf16* vp = qkv + (kvbase + wave * 16) * QKV_N + DIM + NKV * HD + g * HD + lane;
    bf16 vr[16];
    #pragma unroll
    for (int j = 0; j < 16; ++j) vr[j] = vp[(size_t)j * QKV_N];
    #pragma unroll
    for (int c = 0; c < 2; ++c) {
      bf16x8 pk = { vr[c*8], vr[c*8+1], vr[c*8+2], vr[c*8+3],
                    vr[c*8+4], vr[c*8+5], vr[c*8+6], vr[c*8+7] };
      *(bf16x8*)((char*)&VTs[0][0] +
          ((lane * 128 + wave * 32 + c * 16) ^ ((lane & 7) << 4))) = pk;
    }
    asm volatile("s_waitcnt vmcnt(0)" ::: "memory");
    __syncthreads();
  }

  int cur = 0;
  for (int kt = 0; kt < nt_loop; ++kt) {
    const bool has_next = (kt + 1) < nt_loop;
    bf16 vr[16];
    if (has_next) {
      #pragma unroll
      for (int i = 0; i < 2; ++i) {
        int chunk = i * 256 + tid;
        int r = chunk >> 3;
        int csrc = ((chunk & 7) << 3) ^ ((r & 7) << 3);
        __builtin_amdgcn_global_load_lds(
            (const __attribute__((address_space(1))) unsigned int*)
                (qkv + (kvbase + (kt + 1) * 64 + r) * QKV_N + DIM + g * HD + csrc),
            (__attribute__((address_space(3))) unsigned int*)(&Kb[cur ^ 1][0] + chunk * 8), 16, 0, 0);
      }
      const bf16* vp = qkv + (kvbase + (kt + 1) * 64 + wave * 16) * QKV_N
                           + DIM + NKV * HD + g * HD + lane;
      #pragma unroll
      for (int j = 0; j < 16; ++j) vr[j] = vp[(size_t)j * QKV_N];
    }

    if (kt <= last_kt) {
      const bf16* kb = &Kb[cur][0];
      const bf16* vt = &VTs[cur][0];

      // ---- S^T = K Q^T : z[f][nt], lane = (q=f*16+l15, k=nt*16+l4*4+r) ----
      f32x4 z[2][4];
      #pragma unroll
      for (int f = 0; f < 2; ++f)
        #pragma unroll
        for (int nt = 0; nt < 4; ++nt) z[f][nt] = (f32x4){0.f, 0.f, 0.f, 0.f};
      #pragma unroll
      for (int nt = 0; nt < 4; ++nt)
        #pragma unroll
        for (int kk = 0; kk < 2; ++kk) {
          bf16x8 kf = *(const bf16x8*)((const char*)kb +
              (((nt * 16 + l15) * 128 + (kk * 32 + l4 * 8) * 2) ^ ((l15 & 7) << 4)));
          z[0][nt] = __builtin_amdgcn_mfma_f32_16x16x32_bf16(kf, qf[0][kk], z[0][nt], 0, 0, 0);
          z[1][nt] = __builtin_amdgcn_mfma_f32_16x16x32_bf16(kf, qf[1][kk], z[1][nt], 0, 0, 0);
        }

      const bool domask = (kt == last_kt);
      bf16* pbw = &Pb[wave][0];

      #pragma unroll
      for (int f = 0; f < 2; ++f) {
        const int qg = qbase + f * 16 + l15;
        // in-place scale + mask
        #pragma unroll
        for (int nt = 0; nt < 4; ++nt)
          #pragma unroll
          for (int r = 0; r < 4; ++r) {
            float v = z[f][nt][r] * SCALE2;
            if (domask && (kt * 64 + nt * 16 + l4 * 4 + r > qg)) v = -INFINITY;
            z[f][nt][r] = v;
          }

        // row max: 15 in-register + 2 cross-group shfl (q=l15 lane-local)
        float vm = z[f][0][0];
        #pragma unroll
        for (int nt = 0; nt < 4; ++nt)
          #pragma unroll
          for (int r = 0; r < 4; ++r) vm = fmaxf(vm, z[f][nt][r]);
        vm = fmaxf(vm, __shfl_xor(vm, 16));
        vm = fmaxf(vm, __shfl_xor(vm, 32));
        float mnew = fmaxf(m_run[f], vm);
        float alpha = __builtin_amdgcn_exp2f(m_run[f] - mnew);
        m_run[f] = mnew;

        // P = exp2(z - m) in place; row sum
        float ps = 0.f;
        #pragma unroll
        for (int nt = 0; nt < 4; ++nt)
          #pragma unroll
          for (int r = 0; r < 4; ++r) {
            float pv = __builtin_amdgcn_exp2f(z[f][nt][r] - mnew);
            z[f][nt][r] = pv;
            ps += pv;
          }
        ps += __shfl_xor(ps, 16);
        ps += __shfl_xor(ps, 32);
        l_run[f] = l_run[f] * alpha + ps;

        // O^T rescale: col q=l15 matches this lane -> lane-local alpha
        #pragma unroll
        for (int dt = 0; dt < 4; ++dt)
          #pragma unroll
          for (int r = 0; r < 4; ++r) oacc[f][dt][r] *= alpha;

        // packed P write: row q=f*16+l15, 4 consecutive k -> b64
        const int row = f * 16 + l15;
        #pragma unroll
        for (int nt = 0; nt < 4; ++nt) {
          bf16x4 pk = { (bf16)z[f][nt][0], (bf16)z[f][nt][1],
                        (bf16)z[f][nt][2], (bf16)z[f][nt][3] };
          *(bf16x4*)((char*)pbw + ((row * 128 + nt * 32 + l4 * 8) ^ ((row & 7) << 4))) = pk;
        }
      }

      // ---- O^T += V^T P^T : mfma(A=V^T frag, B=P^T frag) ----
      #pragma unroll
      for (int kk = 0; kk < 2; ++kk) {
        bf16x8 pf0 = *(const bf16x8*)((const char*)pbw +
            ((l15 * 128 + kk * 64 + l4 * 16) ^ ((l15 & 7) << 4)));
        bf16x8 pf1 = *(const bf16x8*)((const char*)pbw +
            (((16 + l15) * 128 + kk * 64 + l4 * 16) ^ ((l15 & 7) << 4)));
        #pragma unroll
        for (int dt = 0; dt < 4; ++dt) {
          bf16x8 vf = *(const bf16x8*)((const char*)vt +
              (((dt * 16 + l15) * 128 + (kk * 32 + l4 * 8) * 2) ^ ((l15 & 7) << 4)));
          oacc[0][dt] = __builtin_amdgcn_mfma_f32_16x16x32_bf16(vf, pf0, oacc[0][dt], 0, 0, 0);
          oacc[1][dt] = __builtin_amdgcn_mfma_f32_16x16x32_bf16(vf, pf1, oacc[1][dt], 0, 0, 0);
        }
      }
    }

    if (has_next) {
      #pragma unroll
      for (int c = 0; c < 2; ++c) {
        bf16x8 pk = { vr[c*8], vr[c*8+1], vr[c*8+2], vr[c*8+3],
                      vr[c*8+4], vr[c*8+5], vr[c*8+6], vr[c*8+7] };
        *(bf16x8*)((char*)&VTs[cur ^ 1][0] +
            ((lane * 128 + wave * 32 + c * 16) ^ ((lane & 7) << 4))) = pk;
      }
      asm volatile("s_waitcnt vmcnt(0)" ::: "memory");
      __syncthreads();
      cur ^= 1;
    }
  }

  // ---- epilogue: O^T -> y. q = qbase+f*16+l15 (lane-local l), d = dt*16+l4*4+r ----
  #pragma unroll
  for (int f = 0; f < 2; ++f) {
    float linv = __builtin_amdgcn_rcpf(l_run[f]);
    bf16* yp = y + ((size_t)b * T_SEQ + qbase + f * 16 + l15) * DIM + h * HD + l4 * 4;
    #pragma unroll
    for (int dt = 0; dt < 4; ++dt) {
      bf16x4 ov = { (bf16)(oacc[f][dt][0] * linv), (bf16)(oacc[f][dt][1] * linv),
                    (bf16)(oacc[f][dt][2] * linv), (bf16)(oacc[f][dt][3] * linv) };
      *(bf16x4*)(yp + dt * 16) = ov;
    }
  }
}

// ---------------- launch ----------------
extern "C" void kernel_launch(void* const* d_in, const int* in_sizes, int n_in,
                              void* d_out, int out_size, void* d_ws, size_t ws_size,
                              hipStream_t stream) {
  const float* x    = (const float*)d_in[0];
  const float* cosb = (const float*)d_in[1];
  const float* sinb = (const float*)d_in[2];
  const float* wq   = (const float*)d_in[3];
  const float* wk   = (const float*)d_in[4];
  const float* wv   = (const float*)d_in[5];
  const float* wo   = (const float*)d_in[6];
  float* out = (float*)d_out;

  bf16* xb   = (bf16*)d_ws;                           // 4096*2048
  bf16* wqkv = xb + (size_t)MROWS * DIM;              // 3072*2048
  bf16* wob  = wqkv + (size_t)QKV_N * DIM;            // 2048*2048
  bf16* qkv  = wob + (size_t)DIM * DIM;               // 4096*3072
  bf16* y    = qkv + (size_t)MROWS * QKV_N;           // 4096*2048

  cast_kernel<<<2048, 256, 0, stream>>>(x, xb, MROWS * DIM);
  cast_kernel<<<2048, 256, 0, stream>>>(wq, wqkv, DIM * DIM);
  cast_kernel<<<512, 256, 0, stream>>>(wk, wqkv + (size_t)DIM * DIM, NKV * HD * DIM);
  cast_kernel<<<512, 256, 0, stream>>>(wv, wqkv + (size_t)(DIM + NKV * HD) * DIM, NKV * HD * DIM);
  cast_kernel<<<2048, 256, 0, stream>>>(wo, wob, DIM * DIM);

  // QKV projection: M=4096, N=3072, K=2048 (768 blocks, XCD-swizzled)
  gemm_bt<bf16><<<768, 256, 0, stream>>>(xb, wqkv, qkv, MROWS, QKV_N, DIM, 768 / 8);

  // RoPE on q,k
  rope_kernel<<<(MROWS * 160) / 256, 256, 0, stream>>>(qkv, cosb, sinb);

  // attention: one 128-row strip per 256-thr block, longest-first dispatch
  attn_kernel<<<dim3(NH, 16, 2), 256, 0, stream>>>(qkv, y);

  // output projection: M=4096, N=2048, K=2048 (512 blocks, XCD-swizzled)
  gemm_bt<float><<<512, 256, 0, stream>>>(y, wob, out, MROWS, DIM, DIM, 512 / 8);
}

// Round 9
// 242.862 us; speedup vs baseline: 1.4942x; 1.1201x over previous
//
#include <hip/hip_runtime.h>

typedef __bf16 bf16;
typedef __attribute__((ext_vector_type(8))) __bf16 bf16x8;
typedef __attribute__((ext_vector_type(4))) __bf16 bf16x4;
typedef __attribute__((ext_vector_type(4))) float f32x4;

constexpr int T_SEQ = 2048;
constexpr int DIM   = 2048;
constexpr int NH    = 32;
constexpr int NKV   = 8;
constexpr int HD    = 64;
constexpr int QKV_N = DIM + 2 * NKV * HD;   // 3072
constexpr int MROWS = 2 * T_SEQ;            // 4096 (B*T)

// ---------------- cast f32 -> bf16 ----------------
__global__ void cast_kernel(const float* __restrict__ in, bf16* __restrict__ out, int n) {
  int stride = gridDim.x * blockDim.x * 4;
  for (int i = (blockIdx.x * blockDim.x + threadIdx.x) * 4; i < n; i += stride) {
    float4 v = *(const float4*)(in + i);
    bf16x4 o = { (bf16)v.x, (bf16)v.y, (bf16)v.z, (bf16)v.w };
    *(bf16x4*)(out + i) = o;
  }
}

// ---------------- GEMM: C[m][n] = sum_k A[m][k] * W[n][k] ----------------
// BM=256 BN=128 BK=64, 512 thr (8 waves, 4M x 2N, 64x64/wave).
// Double-buffered LDS (96KB), XOR-swizzled (T2) via pre-swizzled global src.
// stage(t+1) issued at P0 of tile t; single vmcnt(0)+raw-barrier at tile top
// (loads get a full tile to land). 2 k-slice phases with setprio'd MFMA (T5).
// Grid 1-D, bn-major + XCD chunking. Requires M == 4096 (bm = (wg&15)*256).
template <typename OutT>
__global__ __launch_bounds__(512) void gemm256(const bf16* __restrict__ A,
                                               const bf16* __restrict__ W,
                                               OutT* __restrict__ C,
                                               int N, int K, int cpx) {
  constexpr int BM = 256, BN = 128, BK = 64;
  __shared__ __attribute__((aligned(16))) bf16 Ab[2][BM * BK];
  __shared__ __attribute__((aligned(16))) bf16 Bb[2][BN * BK];
  const int tid = threadIdx.x, lane = tid & 63, wave = tid >> 6;
  const int l15 = lane & 15, l4 = lane >> 4;
  const int orig = blockIdx.x;
  const int wg = (orig & 7) * cpx + (orig >> 3);   // XCD chunking (nwg % 8 == 0)
  const int bm = (wg & 15) * BM;                   // M/256 == 16
  const int bn = (wg >> 4) * BN;                   // bn-major: chunk shares W panel
  const int wm = (wave >> 1) * 64, wn = (wave & 1) * 64;

  f32x4 acc[4][4] = {};

  const int NT = K / BK;
  // ---- stage tile kt into side s: linear LDS dest, pre-swizzled global col ----
  auto stage = [&](int s, int k0) {
    #pragma unroll
    for (int i = 0; i < 4; ++i) {                  // A: 256x64 = 32KB = 4 x 512thr x 16B
      int c = i * 512 + tid;
      int row = c >> 3;
      int gc = ((c & 7) ^ (row & 7)) << 3;
      __builtin_amdgcn_global_load_lds(
          (const __attribute__((address_space(1))) unsigned int*)(A + (size_t)(bm + row) * K + k0 + gc),
          (__attribute__((address_space(3))) unsigned int*)(&Ab[s][0] + c * 8), 16, 0, 0);
    }
    #pragma unroll
    for (int i = 0; i < 2; ++i) {                  // B: 128x64 = 16KB = 2 issues
      int c = i * 512 + tid;
      int row = c >> 3;
      int gc = ((c & 7) ^ (row & 7)) << 3;
      __builtin_amdgcn_global_load_lds(
          (const __attribute__((address_space(1))) unsigned int*)(W + (size_t)(bn + row) * K + k0 + gc),
          (__attribute__((address_space(3))) unsigned int*)(&Bb[s][0] + c * 8), 16, 0, 0);
    }
  };

  stage(0, 0);

  for (int t = 0; t < NT; ++t) {
    const int d = t & 1;
    // ---- tile boundary: own stage loads landed -> barrier -> all visible ----
    asm volatile("s_waitcnt vmcnt(0)" ::: "memory");
    __builtin_amdgcn_s_barrier();
    __builtin_amdgcn_sched_barrier(0);

    bf16x8 af[4], bfr[4];
    // ---- P0 (kk=0): reads + prefetch next tile ----
    #pragma unroll
    for (int mi = 0; mi < 4; ++mi) {
      int row = wm + mi * 16 + l15;
      af[mi] = *(const bf16x8*)((const char*)&Ab[d][0] + row * 128 + ((l4 ^ (row & 7)) << 4));
    }
    #pragma unroll
    for (int ni = 0; ni < 4; ++ni) {
      int row = wn + ni * 16 + l15;
      bfr[ni] = *(const bf16x8*)((const char*)&Bb[d][0] + row * 128 + ((l4 ^ (row & 7)) << 4));
    }
    if (t + 1 < NT) stage(d ^ 1, (t + 1) * BK);
    __builtin_amdgcn_s_barrier();
    __builtin_amdgcn_s_setprio(1);
    #pragma unroll
    for (int mi = 0; mi < 4; ++mi)
      #pragma unroll
      for (int ni = 0; ni < 4; ++ni)
        acc[mi][ni] = __builtin_amdgcn_mfma_f32_16x16x32_bf16(af[mi], bfr[ni], acc[mi][ni], 0, 0, 0);
    __builtin_amdgcn_s_setprio(0);
    __builtin_amdgcn_s_barrier();

    // ---- P1 (kk=1) ----
    #pragma unroll
    for (int mi = 0; mi < 4; ++mi) {
      int row = wm + mi * 16 + l15;
      af[mi] = *(const bf16x8*)((const char*)&Ab[d][0] + row * 128 + (((4 + l4) ^ (row & 7)) << 4));
    }
    #pragma unroll
    for (int ni = 0; ni < 4; ++ni) {
      int row = wn + ni * 16 + l15;
      bfr[ni] = *(const bf16x8*)((const char*)&Bb[d][0] + row * 128 + (((4 + l4) ^ (row & 7)) << 4));
    }
    __builtin_amdgcn_s_barrier();
    __builtin_amdgcn_s_setprio(1);
    #pragma unroll
    for (int mi = 0; mi < 4; ++mi)
      #pragma unroll
      for (int ni = 0; ni < 4; ++ni)
        acc[mi][ni] = __builtin_amdgcn_mfma_f32_16x16x32_bf16(af[mi], bfr[ni], acc[mi][ni], 0, 0, 0);
    __builtin_amdgcn_s_setprio(0);
    // loop-top vmcnt+barrier is the P1-end sync
  }

  // ---- epilogue ----
  #pragma unroll
  for (int mi = 0; mi < 4; ++mi)
    #pragma unroll
    for (int ni = 0; ni < 4; ++ni) {
      size_t row = (size_t)bm + wm + mi * 16 + l4 * 4;
      int col = bn + wn + ni * 16 + l15;
      #pragma unroll
      for (int r = 0; r < 4; ++r)
        C[(row + r) * N + col] = (OutT)acc[mi][ni][r];
    }
}

// ---------------- RoPE, vectorized: 16 bf16 (8 pairs) per thread ----------------
__global__ void rope_kernel(bf16* __restrict__ qkv, const float* __restrict__ cs,
                            const float* __restrict__ sn) {
  int idx = blockIdx.x * blockDim.x + threadIdx.x;   // MROWS*160 total
  int m = idx / 160;
  int ch = idx - m * 160;
  int t = m & (T_SEQ - 1);
  int col, c;
  if (ch < 128) { int hh = ch >> 2; c = ch & 3; col = hh * 64 + c * 16; }
  else          { int ch2 = ch - 128; int hh = ch2 >> 2; c = ch2 & 3; col = DIM + hh * 64 + c * 16; }
  bf16* ptr = qkv + (size_t)m * QKV_N + col;
  bf16x8 v0 = *(bf16x8*)ptr, v1 = *(bf16x8*)(ptr + 8);
  const float* cp = cs + t * 32 + c * 8;
  const float* sp = sn + t * 32 + c * 8;
  float4 c0 = *(const float4*)cp, c1 = *(const float4*)(cp + 4);
  float4 s0 = *(const float4*)sp, s1 = *(const float4*)(sp + 4);
  float cc[8] = {c0.x, c0.y, c0.z, c0.w, c1.x, c1.y, c1.z, c1.w};
  float ss[8] = {s0.x, s0.y, s0.z, s0.w, s1.x, s1.y, s1.z, s1.w};
  bf16x8 o0, o1;
  #pragma unroll
  for (int j = 0; j < 4; ++j) {
    float a = (float)v0[2 * j], b = (float)v0[2 * j + 1];
    o0[2 * j]     = (bf16)(a * cc[j] - b * ss[j]);
    o0[2 * j + 1] = (bf16)(a * ss[j] + b * cc[j]);
  }
  #pragma unroll
  for (int j = 0; j < 4; ++j) {
    float a = (float)v1[2 * j], b = (float)v1[2 * j + 1];
    o1[2 * j]     = (bf16)(a * cc[4 + j] - b * ss[4 + j]);
    o1[2 * j + 1] = (bf16)(a * ss[4 + j] + b * cc[4 + j]);
  }
  *(bf16x8*)ptr = o0;
  *(bf16x8*)(ptr + 8) = o1;
}

// ---------------- Flash attention, causal GQA (unchanged from R8) ----------------
__global__ __launch_bounds__(256, 3) void attn_kernel(const bf16* __restrict__ qkv,
                                                      bf16* __restrict__ y) {
  const int h = blockIdx.x, b = blockIdx.z;
  const int strip = 15 - blockIdx.y;
  const int g = h >> 2;  // kv head
  const int tid = threadIdx.x, lane = tid & 63, wave = tid >> 6;
  const int l15 = lane & 15, l4 = lane >> 4;
  const int qbase = strip * 128 + wave * 32;

  __shared__ __attribute__((aligned(16))) bf16 Kb[2][64 * 64];   // [kv][d], swizzled
  __shared__ __attribute__((aligned(16))) bf16 VTs[2][64 * 64];  // [d][kv], swizzled
  __shared__ __attribute__((aligned(16))) bf16 Pb[4][32 * 64];   // per-wave [q][kv], swizzled

  constexpr float SCALE2 = 0.125f * 1.44269504088896f;  // scale * log2(e)

  bf16x8 qf[2][2];
  #pragma unroll
  for (int f = 0; f < 2; ++f) {
    const bf16* qp = qkv + ((size_t)b * T_SEQ + qbase + f * 16 + l15) * QKV_N + h * HD + l4 * 8;
    qf[f][0] = *(const bf16x8*)(qp);
    qf[f][1] = *(const bf16x8*)(qp + 32);
  }

  f32x4 oacc[2][4] = {};
  float m_run[2] = {-INFINITY, -INFINITY}, l_run[2] = {0.f, 0.f};

  const int last_kt = (qbase + 31) >> 6;
  const int nt_loop = 2 * strip + 2;
  const size_t kvbase = (size_t)b * T_SEQ;

  {
    #pragma unroll
    for (int i = 0; i < 2; ++i) {
      int chunk = i * 256 + tid;
      int r = chunk >> 3;
      int csrc = ((chunk & 7) << 3) ^ ((r & 7) << 3);
      __builtin_amdgcn_global_load_lds(
          (const __attribute__((address_space(1))) unsigned int*)
              (qkv + (kvbase + r) * QKV_N + DIM + g * HD + csrc),
          (__attribute__((address_space(3))) unsigned int*)(&Kb[0][0] + chunk * 8), 16, 0, 0);
    }
    const bf16* vp = qkv + (kvbase + wave * 16) * QKV_N + DIM + NKV * HD + g * HD + lane;
    bf16 vr[16];
    #pragma unroll
    for (int j = 0; j < 16; ++j) vr[j] = vp[(size_t)j * QKV_N];
    #pragma unroll
    for (int c = 0; c < 2; ++c) {
      bf16x8 pk = { vr[c*8], vr[c*8+1], vr[c*8+2], vr[c*8+3],
                    vr[c*8+4], vr[c*8+5], vr[c*8+6], vr[c*8+7] };
      *(bf16x8*)((char*)&VTs[0][0] +
          ((lane * 128 + wave * 32 + c * 16) ^ ((lane & 7) << 4))) = pk;
    }
    asm volatile("s_waitcnt vmcnt(0)" ::: "memory");
    __syncthreads();
  }

  int cur = 0;
  for (int kt = 0; kt < nt_loop; ++kt) {
    const bool has_next = (kt + 1) < nt_loop;
    bf16 vr[16];
    if (has_next) {
      #pragma unroll
      for (int i = 0; i < 2; ++i) {
        int chunk = i * 256 + tid;
        int r = chunk >> 3;
        int csrc = ((chunk & 7) << 3) ^ ((r & 7) << 3);
        __builtin_amdgcn_global_load_lds(
            (const __attribute__((address_space(1))) unsigned int*)
                (qkv + (kvbase + (kt + 1) * 64 + r) * QKV_N + DIM + g * HD + csrc),
            (__attribute__((address_space(3))) unsigned int*)(&Kb[cur ^ 1][0] + chunk * 8), 16, 0, 0);
      }
      const bf16* vp = qkv + (kvbase + (kt + 1) * 64 + wave * 16) * QKV_N
                           + DIM + NKV * HD + g * HD + lane;
      #pragma unroll
      for (int j = 0; j < 16; ++j) vr[j] = vp[(size_t)j * QKV_N];
    }

    if (kt <= last_kt) {
      const bf16* kb = &Kb[cur][0];
      const bf16* vt = &VTs[cur][0];

      f32x4 z[2][4];
      #pragma unroll
      for (int f = 0; f < 2; ++f)
        #pragma unroll
        for (int nt = 0; nt < 4; ++nt) z[f][nt] = (f32x4){0.f, 0.f, 0.f, 0.f};
      #pragma unroll
      for (int nt = 0; nt < 4; ++nt)
        #pragma unroll
        for (int kk = 0; kk < 2; ++kk) {
          bf16x8 kf = *(const bf16x8*)((const char*)kb +
              (((nt * 16 + l15) * 128 + (kk * 32 + l4 * 8) * 2) ^ ((l15 & 7) << 4)));
          z[0][nt] = __builtin_amdgcn_mfma_f32_16x16x32_bf16(kf, qf[0][kk], z[0][nt], 0, 0, 0);
          z[1][nt] = __builtin_amdgcn_mfma_f32_16x16x32_bf16(kf, qf[1][kk], z[1][nt], 0, 0, 0);
        }

      const bool domask = (kt == last_kt);
      bf16* pbw = &Pb[wave][0];

      #pragma unroll
      for (int f = 0; f < 2; ++f) {
        const int qg = qbase + f * 16 + l15;
        #pragma unroll
        for (int nt = 0; nt < 4; ++nt)
          #pragma unroll
          for (int r = 0; r < 4; ++r) {
            float v = z[f][nt][r] * SCALE2;
            if (domask && (kt * 64 + nt * 16 + l4 * 4 + r > qg)) v = -INFINITY;
            z[f][nt][r] = v;
          }

        float vm = z[f][0][0];
        #pragma unroll
        for (int nt = 0; nt < 4; ++nt)
          #pragma unroll
          for (int r = 0; r < 4; ++r) vm = fmaxf(vm, z[f][nt][r]);
        vm = fmaxf(vm, __shfl_xor(vm, 16));
        vm = fmaxf(vm, __shfl_xor(vm, 32));
        float mnew = fmaxf(m_run[f], vm);
        float alpha = __builtin_amdgcn_exp2f(m_run[f] - mnew);
        m_run[f] = mnew;

        float ps = 0.f;
        #pragma unroll
        for (int nt = 0; nt < 4; ++nt)
          #pragma unroll
          for (int r = 0; r < 4; ++r) {
            float pv = __builtin_amdgcn_exp2f(z[f][nt][r] - mnew);
            z[f][nt][r] = pv;
            ps += pv;
          }
        ps += __shfl_xor(ps, 16);
        ps += __shfl_xor(ps, 32);
        l_run[f] = l_run[f] * alpha + ps;

        #pragma unroll
        for (int dt = 0; dt < 4; ++dt)
          #pragma unroll
          for (int r = 0; r < 4; ++r) oacc[f][dt][r] *= alpha;

        const int row = f * 16 + l15;
        #pragma unroll
        for (int nt = 0; nt < 4; ++nt) {
          bf16x4 pk = { (bf16)z[f][nt][0], (bf16)z[f][nt][1],
                        (bf16)z[f][nt][2], (bf16)z[f][nt][3] };
          *(bf16x4*)((char*)pbw + ((row * 128 + nt * 32 + l4 * 8) ^ ((row & 7) << 4))) = pk;
        }
      }

      #pragma unroll
      for (int kk = 0; kk < 2; ++kk) {
        bf16x8 pf0 = *(const bf16x8*)((const char*)pbw +
            ((l15 * 128 + kk * 64 + l4 * 16) ^ ((l15 & 7) << 4)));
        bf16x8 pf1 = *(const bf16x8*)((const char*)pbw +
            (((16 + l15) * 128 + kk * 64 + l4 * 16) ^ ((l15 & 7) << 4)));
        #pragma unroll
        for (int dt = 0; dt < 4; ++dt) {
          bf16x8 vf = *(const bf16x8*)((const char*)vt +
              (((dt * 16 + l15) * 128 + (kk * 32 + l4 * 8) * 2) ^ ((l15 & 7) << 4)));
          oacc[0][dt] = __builtin_amdgcn_mfma_f32_16x16x32_bf16(vf, pf0, oacc[0][dt], 0, 0, 0);
          oacc[1][dt] = __builtin_amdgcn_mfma_f32_16x16x32_bf16(vf, pf1, oacc[1][dt], 0, 0, 0);
        }
      }
    }

    if (has_next) {
      #pragma unroll
      for (int c = 0; c < 2; ++c) {
        bf16x8 pk = { vr[c*8], vr[c*8+1], vr[c*8+2], vr[c*8+3],
                      vr[c*8+4], vr[c*8+5], vr[c*8+6], vr[c*8+7] };
        *(bf16x8*)((char*)&VTs[cur ^ 1][0] +
            ((lane * 128 + wave * 32 + c * 16) ^ ((lane & 7) << 4))) = pk;
      }
      asm volatile("s_waitcnt vmcnt(0)" ::: "memory");
      __syncthreads();
      cur ^= 1;
    }
  }

  #pragma unroll
  for (int f = 0; f < 2; ++f) {
    float linv = __builtin_amdgcn_rcpf(l_run[f]);
    bf16* yp = y + ((size_t)b * T_SEQ + qbase + f * 16 + l15) * DIM + h * HD + l4 * 4;
    #pragma unroll
    for (int dt = 0; dt < 4; ++dt) {
      bf16x4 ov = { (bf16)(oacc[f][dt][0] * linv), (bf16)(oacc[f][dt][1] * linv),
                    (bf16)(oacc[f][dt][2] * linv), (bf16)(oacc[f][dt][3] * linv) };
      *(bf16x4*)(yp + dt * 16) = ov;
    }
  }
}

// ---------------- launch ----------------
extern "C" void kernel_launch(void* const* d_in, const int* in_sizes, int n_in,
                              void* d_out, int out_size, void* d_ws, size_t ws_size,
                              hipStream_t stream) {
  const float* x    = (const float*)d_in[0];
  const float* cosb = (const float*)d_in[1];
  const float* sinb = (const float*)d_in[2];
  const float* wq   = (const float*)d_in[3];
  const float* wk   = (const float*)d_in[4];
  const float* wv   = (const float*)d_in[5];
  const float* wo   = (const float*)d_in[6];
  float* out = (float*)d_out;

  bf16* xb   = (bf16*)d_ws;                           // 4096*2048
  bf16* wqkv = xb + (size_t)MROWS * DIM;              // 3072*2048
  bf16* wob  = wqkv + (size_t)QKV_N * DIM;            // 2048*2048
  bf16* qkv  = wob + (size_t)DIM * DIM;               // 4096*3072
  bf16* y    = qkv + (size_t)MROWS * QKV_N;           // 4096*2048

  cast_kernel<<<2048, 256, 0, stream>>>(x, xb, MROWS * DIM);
  cast_kernel<<<2048, 256, 0, stream>>>(wq, wqkv, DIM * DIM);
  cast_kernel<<<512, 256, 0, stream>>>(wk, wqkv + (size_t)DIM * DIM, NKV * HD * DIM);
  cast_kernel<<<512, 256, 0, stream>>>(wv, wqkv + (size_t)(DIM + NKV * HD) * DIM, NKV * HD * DIM);
  cast_kernel<<<2048, 256, 0, stream>>>(wo, wob, DIM * DIM);

  // QKV projection: M=4096, N=3072, K=2048 -> 16 x 24 = 384 blocks
  gemm256<bf16><<<384, 512, 0, stream>>>(xb, wqkv, qkv, QKV_N, DIM, 384 / 8);

  // RoPE on q,k
  rope_kernel<<<(MROWS * 160) / 256, 256, 0, stream>>>(qkv, cosb, sinb);

  // attention: one 128-row strip per 256-thr block, longest-first dispatch
  attn_kernel<<<dim3(NH, 16, 2), 256, 0, stream>>>(qkv, y);

  // output projection: M=4096, N=2048, K=2048 -> 16 x 16 = 256 blocks
  gemm256<float><<<256, 512, 0, stream>>>(y, wob, out, DIM, DIM, 256 / 8);
}

// Round 10
// 225.133 us; speedup vs baseline: 1.6119x; 1.0788x over previous
//
#include <hip/hip_runtime.h>

typedef __bf16 bf16;
typedef __attribute__((ext_vector_type(8))) __bf16 bf16x8;
typedef __attribute__((ext_vector_type(4))) __bf16 bf16x4;
typedef __attribute__((ext_vector_type(4))) float f32x4;

constexpr int T_SEQ = 2048;
constexpr int DIM   = 2048;
constexpr int NH    = 32;
constexpr int NKV   = 8;
constexpr int HD    = 64;
constexpr int QKV_N = DIM + 2 * NKV * HD;   // 3072
constexpr int MROWS = 2 * T_SEQ;            // 4096 (B*T)

// ---------------- cast f32 -> bf16 ----------------
__global__ void cast_kernel(const float* __restrict__ in, bf16* __restrict__ out, int n) {
  int stride = gridDim.x * blockDim.x * 4;
  for (int i = (blockIdx.x * blockDim.x + threadIdx.x) * 4; i < n; i += stride) {
    float4 v = *(const float4*)(in + i);
    bf16x4 o = { (bf16)v.x, (bf16)v.y, (bf16)v.z, (bf16)v.w };
    *(bf16x4*)(out + i) = o;
  }
}

// ---------------- GEMM: C[m][n] = sum_k A[m][k] * W[n][k] (unchanged R9) ----------------
template <typename OutT>
__global__ __launch_bounds__(512) void gemm256(const bf16* __restrict__ A,
                                               const bf16* __restrict__ W,
                                               OutT* __restrict__ C,
                                               int N, int K, int cpx) {
  constexpr int BM = 256, BN = 128, BK = 64;
  __shared__ __attribute__((aligned(16))) bf16 Ab[2][BM * BK];
  __shared__ __attribute__((aligned(16))) bf16 Bb[2][BN * BK];
  const int tid = threadIdx.x, lane = tid & 63, wave = tid >> 6;
  const int l15 = lane & 15, l4 = lane >> 4;
  const int orig = blockIdx.x;
  const int wg = (orig & 7) * cpx + (orig >> 3);
  const int bm = (wg & 15) * BM;
  const int bn = (wg >> 4) * BN;
  const int wm = (wave >> 1) * 64, wn = (wave & 1) * 64;

  f32x4 acc[4][4] = {};

  const int NT = K / BK;
  auto stage = [&](int s, int k0) {
    #pragma unroll
    for (int i = 0; i < 4; ++i) {
      int c = i * 512 + tid;
      int row = c >> 3;
      int gc = ((c & 7) ^ (row & 7)) << 3;
      __builtin_amdgcn_global_load_lds(
          (const __attribute__((address_space(1))) unsigned int*)(A + (size_t)(bm + row) * K + k0 + gc),
          (__attribute__((address_space(3))) unsigned int*)(&Ab[s][0] + c * 8), 16, 0, 0);
    }
    #pragma unroll
    for (int i = 0; i < 2; ++i) {
      int c = i * 512 + tid;
      int row = c >> 3;
      int gc = ((c & 7) ^ (row & 7)) << 3;
      __builtin_amdgcn_global_load_lds(
          (const __attribute__((address_space(1))) unsigned int*)(W + (size_t)(bn + row) * K + k0 + gc),
          (__attribute__((address_space(3))) unsigned int*)(&Bb[s][0] + c * 8), 16, 0, 0);
    }
  };

  stage(0, 0);

  for (int t = 0; t < NT; ++t) {
    const int d = t & 1;
    asm volatile("s_waitcnt vmcnt(0)" ::: "memory");
    __builtin_amdgcn_s_barrier();
    __builtin_amdgcn_sched_barrier(0);

    bf16x8 af[4], bfr[4];
    #pragma unroll
    for (int mi = 0; mi < 4; ++mi) {
      int row = wm + mi * 16 + l15;
      af[mi] = *(const bf16x8*)((const char*)&Ab[d][0] + row * 128 + ((l4 ^ (row & 7)) << 4));
    }
    #pragma unroll
    for (int ni = 0; ni < 4; ++ni) {
      int row = wn + ni * 16 + l15;
      bfr[ni] = *(const bf16x8*)((const char*)&Bb[d][0] + row * 128 + ((l4 ^ (row & 7)) << 4));
    }
    if (t + 1 < NT) stage(d ^ 1, (t + 1) * BK);
    __builtin_amdgcn_s_barrier();
    __builtin_amdgcn_s_setprio(1);
    #pragma unroll
    for (int mi = 0; mi < 4; ++mi)
      #pragma unroll
      for (int ni = 0; ni < 4; ++ni)
        acc[mi][ni] = __builtin_amdgcn_mfma_f32_16x16x32_bf16(af[mi], bfr[ni], acc[mi][ni], 0, 0, 0);
    __builtin_amdgcn_s_setprio(0);
    __builtin_amdgcn_s_barrier();

    #pragma unroll
    for (int mi = 0; mi < 4; ++mi) {
      int row = wm + mi * 16 + l15;
      af[mi] = *(const bf16x8*)((const char*)&Ab[d][0] + row * 128 + (((4 + l4) ^ (row & 7)) << 4));
    }
    #pragma unroll
    for (int ni = 0; ni < 4; ++ni) {
      int row = wn + ni * 16 + l15;
      bfr[ni] = *(const bf16x8*)((const char*)&Bb[d][0] + row * 128 + (((4 + l4) ^ (row & 7)) << 4));
    }
    __builtin_amdgcn_s_barrier();
    __builtin_amdgcn_s_setprio(1);
    #pragma unroll
    for (int mi = 0; mi < 4; ++mi)
      #pragma unroll
      for (int ni = 0; ni < 4; ++ni)
        acc[mi][ni] = __builtin_amdgcn_mfma_f32_16x16x32_bf16(af[mi], bfr[ni], acc[mi][ni], 0, 0, 0);
    __builtin_amdgcn_s_setprio(0);
  }

  #pragma unroll
  for (int mi = 0; mi < 4; ++mi)
    #pragma unroll
    for (int ni = 0; ni < 4; ++ni) {
      size_t row = (size_t)bm + wm + mi * 16 + l4 * 4;
      int col = bn + wn + ni * 16 + l15;
      #pragma unroll
      for (int r = 0; r < 4; ++r)
        C[(row + r) * N + col] = (OutT)acc[mi][ni][r];
    }
}

// ---------------- RoPE, vectorized (unchanged) ----------------
__global__ void rope_kernel(bf16* __restrict__ qkv, const float* __restrict__ cs,
                            const float* __restrict__ sn) {
  int idx = blockIdx.x * blockDim.x + threadIdx.x;
  int m = idx / 160;
  int ch = idx - m * 160;
  int t = m & (T_SEQ - 1);
  int col, c;
  if (ch < 128) { int hh = ch >> 2; c = ch & 3; col = hh * 64 + c * 16; }
  else          { int ch2 = ch - 128; int hh = ch2 >> 2; c = ch2 & 3; col = DIM + hh * 64 + c * 16; }
  bf16* ptr = qkv + (size_t)m * QKV_N + col;
  bf16x8 v0 = *(bf16x8*)ptr, v1 = *(bf16x8*)(ptr + 8);
  const float* cp = cs + t * 32 + c * 8;
  const float* sp = sn + t * 32 + c * 8;
  float4 c0 = *(const float4*)cp, c1 = *(const float4*)(cp + 4);
  float4 s0 = *(const float4*)sp, s1 = *(const float4*)(sp + 4);
  float cc[8] = {c0.x, c0.y, c0.z, c0.w, c1.x, c1.y, c1.z, c1.w};
  float ss[8] = {s0.x, s0.y, s0.z, s0.w, s1.x, s1.y, s1.z, s1.w};
  bf16x8 o0, o1;
  #pragma unroll
  for (int j = 0; j < 4; ++j) {
    float a = (float)v0[2 * j], b = (float)v0[2 * j + 1];
    o0[2 * j]     = (bf16)(a * cc[j] - b * ss[j]);
    o0[2 * j + 1] = (bf16)(a * ss[j] + b * cc[j]);
  }
  #pragma unroll
  for (int j = 0; j < 4; ++j) {
    float a = (float)v1[2 * j], b = (float)v1[2 * j + 1];
    o1[2 * j]     = (bf16)(a * cc[4 + j] - b * ss[4 + j]);
    o1[2 * j + 1] = (bf16)(a * ss[4 + j] + b * cc[4 + j]);
  }
  *(bf16x8*)ptr = o0;
  *(bf16x8*)(ptr + 8) = o1;
}

// ---------------- Flash attention, causal GQA ----------------
// grid (NH, 16, B); 512 thr = 8 waves x 16 q-rows = ONE 128-row strip/block.
// 48 KB LDS -> 3 blocks/CU = 24 waves/CU (2x R9's wave slots).
// Swapped QK^T/PV (lane owns q=l15), raw-domain max + fma-folded exp2,
// defer-max (THR=8). Double-buffered K (glds) + V (reg-gather), 1 barrier/tile.
__global__ __launch_bounds__(512, 4) void attn_kernel(const bf16* __restrict__ qkv,
                                                      bf16* __restrict__ y) {
  const int h = blockIdx.x, b = blockIdx.z;
  const int strip = 15 - blockIdx.y;              // longest-first (LPT)
  const int g = h >> 2;
  const int tid = threadIdx.x, lane = tid & 63, wave = tid >> 6;
  const int l15 = lane & 15, l4 = lane >> 4;
  const int qbase = strip * 128 + wave * 16;      // 16 rows per wave

  __shared__ __attribute__((aligned(16))) bf16 Kb[2][64 * 64];   // [kv][d], swizzled
  __shared__ __attribute__((aligned(16))) bf16 VTs[2][64 * 64];  // [d][kv], swizzled
  __shared__ __attribute__((aligned(16))) bf16 Pb[8][16 * 64];   // per-wave [q][kv], swizzled

  constexpr float SCALE2 = 0.125f * 1.44269504088896f;  // scale * log2(e)
  constexpr float THR_RAW = 8.0f / SCALE2;              // defer-max threshold (raw units)

  // Q fragments (B-operand of swapped QK^T): rows qbase+l15
  bf16x8 qf[2];
  {
    const bf16* qp = qkv + ((size_t)b * T_SEQ + qbase + l15) * QKV_N + h * HD + l4 * 8;
    qf[0] = *(const bf16x8*)(qp);
    qf[1] = *(const bf16x8*)(qp + 32);
  }

  // oacc[dt] = O^T fragment: row d = dt*16 + l4*4 + r, col q = l15
  f32x4 oacc[4] = {};
  float m_run = -INFINITY, l_run = 0.f;    // m_run in RAW logit units

  const int last_kt = (qbase + 15) >> 6;
  const int nt_loop = 2 * strip + 2;
  const size_t kvbase = (size_t)b * T_SEQ;

  // ---- prologue: stage tile 0 into buffer 0 ----
  {
    int r = tid >> 3;
    int csrc = ((tid & 7) << 3) ^ ((r & 7) << 3);
    __builtin_amdgcn_global_load_lds(
        (const __attribute__((address_space(1))) unsigned int*)
            (qkv + (kvbase + r) * QKV_N + DIM + g * HD + csrc),
        (__attribute__((address_space(3))) unsigned int*)(&Kb[0][0] + tid * 8), 16, 0, 0);
    const bf16* vp = qkv + (kvbase + wave * 8) * QKV_N + DIM + NKV * HD + g * HD + lane;
    bf16x8 vr;
    #pragma unroll
    for (int j = 0; j < 8; ++j) vr[j] = vp[(size_t)j * QKV_N];
    *(bf16x8*)((char*)&VTs[0][0] + ((lane * 128 + wave * 16) ^ ((lane & 7) << 4))) = vr;
    asm volatile("s_waitcnt vmcnt(0)" ::: "memory");
    __syncthreads();
  }

  int cur = 0;
  for (int kt = 0; kt < nt_loop; ++kt) {
    const bool has_next = (kt + 1) < nt_loop;
    bf16x8 vr;
    if (has_next) {
      int r = tid >> 3;
      int csrc = ((tid & 7) << 3) ^ ((r & 7) << 3);
      __builtin_amdgcn_global_load_lds(
          (const __attribute__((address_space(1))) unsigned int*)
              (qkv + (kvbase + (kt + 1) * 64 + r) * QKV_N + DIM + g * HD + csrc),
          (__attribute__((address_space(3))) unsigned int*)(&Kb[cur ^ 1][0] + tid * 8), 16, 0, 0);
      const bf16* vp = qkv + (kvbase + (kt + 1) * 64 + wave * 8) * QKV_N
                           + DIM + NKV * HD + g * HD + lane;
      #pragma unroll
      for (int j = 0; j < 8; ++j) vr[j] = vp[(size_t)j * QKV_N];
    }

    if (kt <= last_kt) {
      const bf16* kb = &Kb[cur][0];
      const bf16* vt = &VTs[cur][0];

      // ---- S^T = K Q^T : z[nt], lane = (q=l15, k=nt*16+l4*4+r), RAW ----
      f32x4 z[4];
      #pragma unroll
      for (int nt = 0; nt < 4; ++nt) z[nt] = (f32x4){0.f, 0.f, 0.f, 0.f};
      #pragma unroll
      for (int nt = 0; nt < 4; ++nt)
        #pragma unroll
        for (int kk = 0; kk < 2; ++kk) {
          bf16x8 kf = *(const bf16x8*)((const char*)kb +
              (((nt * 16 + l15) * 128 + (kk * 32 + l4 * 8) * 2) ^ ((l15 & 7) << 4)));
          z[nt] = __builtin_amdgcn_mfma_f32_16x16x32_bf16(kf, qf[kk], z[nt], 0, 0, 0);
        }

      // ---- causal mask (diag tile only), raw domain ----
      if (kt == last_kt) {
        const int qg = qbase + l15;
        #pragma unroll
        for (int nt = 0; nt < 4; ++nt)
          #pragma unroll
          for (int r = 0; r < 4; ++r)
            if (kt * 64 + nt * 16 + l4 * 4 + r > qg) z[nt][r] = -INFINITY;
      }

      // ---- row max (raw): 15 reg ops + 2 shfl ----
      float vm = z[0][0];
      #pragma unroll
      for (int nt = 0; nt < 4; ++nt)
        #pragma unroll
        for (int r = 0; r < 4; ++r) vm = fmaxf(vm, z[nt][r]);
      vm = fmaxf(vm, __shfl_xor(vm, 16));
      vm = fmaxf(vm, __shfl_xor(vm, 32));

      // ---- defer-max: rescale only when max grew past THR ----
      if (!__all(vm - m_run <= THR_RAW)) {
        float mnew = fmaxf(m_run, vm);
        float alpha = __builtin_amdgcn_exp2f((m_run - mnew) * SCALE2);
        l_run *= alpha;
        #pragma unroll
        for (int dt = 0; dt < 4; ++dt)
          #pragma unroll
          for (int r = 0; r < 4; ++r) oacc[dt][r] *= alpha;
        m_run = mnew;
      }
      const float ms = m_run * SCALE2;

      // ---- P = exp2(z*S - ms) in place; row sum ----
      float ps = 0.f;
      #pragma unroll
      for (int nt = 0; nt < 4; ++nt)
        #pragma unroll
        for (int r = 0; r < 4; ++r) {
          float pv = __builtin_amdgcn_exp2f(__builtin_fmaf(z[nt][r], SCALE2, -ms));
          z[nt][r] = pv;
          ps += pv;
        }
      ps += __shfl_xor(ps, 16);
      ps += __shfl_xor(ps, 32);
      l_run += ps;

      // ---- packed P write: row q=l15, 4 consecutive k -> b64 ----
      bf16* pbw = &Pb[wave][0];
      #pragma unroll
      for (int nt = 0; nt < 4; ++nt) {
        bf16x4 pk = { (bf16)z[nt][0], (bf16)z[nt][1], (bf16)z[nt][2], (bf16)z[nt][3] };
        *(bf16x4*)((char*)pbw + ((l15 * 128 + nt * 32 + l4 * 8) ^ ((l15 & 7) << 4))) = pk;
      }

      // ---- O^T += V^T P^T ----
      #pragma unroll
      for (int kk = 0; kk < 2; ++kk) {
        bf16x8 pf = *(const bf16x8*)((const char*)pbw +
            ((l15 * 128 + kk * 64 + l4 * 16) ^ ((l15 & 7) << 4)));
        #pragma unroll
        for (int dt = 0; dt < 4; ++dt) {
          bf16x8 vf = *(const bf16x8*)((const char*)vt +
              (((dt * 16 + l15) * 128 + (kk * 32 + l4 * 8) * 2) ^ ((l15 & 7) << 4)));
          oacc[dt] = __builtin_amdgcn_mfma_f32_16x16x32_bf16(vf, pf, oacc[dt], 0, 0, 0);
        }
      }
    }

    if (has_next) {
      *(bf16x8*)((char*)&VTs[cur ^ 1][0] + ((lane * 128 + wave * 16) ^ ((lane & 7) << 4))) = vr;
      asm volatile("s_waitcnt vmcnt(0)" ::: "memory");
      __syncthreads();
      cur ^= 1;
    }
  }

  // ---- epilogue: O^T -> y. q = qbase+l15, d = dt*16+l4*4+r ----
  {
    float linv = __builtin_amdgcn_rcpf(l_run);
    bf16* yp = y + ((size_t)b * T_SEQ + qbase + l15) * DIM + h * HD + l4 * 4;
    #pragma unroll
    for (int dt = 0; dt < 4; ++dt) {
      bf16x4 ov = { (bf16)(oacc[dt][0] * linv), (bf16)(oacc[dt][1] * linv),
                    (bf16)(oacc[dt][2] * linv), (bf16)(oacc[dt][3] * linv) };
      *(bf16x4*)(yp + dt * 16) = ov;
    }
  }
}

// ---------------- launch ----------------
extern "C" void kernel_launch(void* const* d_in, const int* in_sizes, int n_in,
                              void* d_out, int out_size, void* d_ws, size_t ws_size,
                              hipStream_t stream) {
  const float* x    = (const float*)d_in[0];
  const float* cosb = (const float*)d_in[1];
  const float* sinb = (const float*)d_in[2];
  const float* wq   = (const float*)d_in[3];
  const float* wk   = (const float*)d_in[4];
  const float* wv   = (const float*)d_in[5];
  const float* wo   = (const float*)d_in[6];
  float* out = (float*)d_out;

  bf16* xb   = (bf16*)d_ws;                           // 4096*2048
  bf16* wqkv = xb + (size_t)MROWS * DIM;              // 3072*2048
  bf16* wob  = wqkv + (size_t)QKV_N * DIM;            // 2048*2048
  bf16* qkv  = wob + (size_t)DIM * DIM;               // 4096*3072
  bf16* y    = qkv + (size_t)MROWS * QKV_N;           // 4096*2048

  cast_kernel<<<2048, 256, 0, stream>>>(x, xb, MROWS * DIM);
  cast_kernel<<<2048, 256, 0, stream>>>(wq, wqkv, DIM * DIM);
  cast_kernel<<<512, 256, 0, stream>>>(wk, wqkv + (size_t)DIM * DIM, NKV * HD * DIM);
  cast_kernel<<<512, 256, 0, stream>>>(wv, wqkv + (size_t)(DIM + NKV * HD) * DIM, NKV * HD * DIM);
  cast_kernel<<<2048, 256, 0, stream>>>(wo, wob, DIM * DIM);

  // QKV projection: M=4096, N=3072, K=2048 -> 384 blocks
  gemm256<bf16><<<384, 512, 0, stream>>>(xb, wqkv, qkv, QKV_N, DIM, 384 / 8);

  // RoPE on q,k
  rope_kernel<<<(MROWS * 160) / 256, 256, 0, stream>>>(qkv, cosb, sinb);

  // attention: one 128-row strip per 512-thr block (8 waves x 16 rows)
  attn_kernel<<<dim3(NH, 16, 2), 512, 0, stream>>>(qkv, y);

  // output projection: M=4096, N=2048, K=2048 -> 256 blocks
  gemm256<float><<<256, 512, 0, stream>>>(y, wob, out, DIM, DIM, 256 / 8);
}

// Round 11
// 192.831 us; speedup vs baseline: 1.8819x; 1.1675x over previous
//
#include <hip/hip_runtime.h>

typedef __bf16 bf16;
typedef __attribute__((ext_vector_type(8))) __bf16 bf16x8;
typedef __attribute__((ext_vector_type(4))) __bf16 bf16x4;
typedef __attribute__((ext_vector_type(4))) float f32x4;

constexpr int T_SEQ = 2048;
constexpr int DIM   = 2048;
constexpr int NH    = 32;
constexpr int NKV   = 8;
constexpr int HD    = 64;
constexpr int QKV_N = DIM + 2 * NKV * HD;   // 3072
constexpr int MROWS = 2 * T_SEQ;            // 4096 (B*T)

// ---------------- cast f32 -> bf16 (x) ----------------
__global__ void cast_kernel(const float* __restrict__ in, bf16* __restrict__ out, int n) {
  int stride = gridDim.x * blockDim.x * 4;
  for (int i = (blockIdx.x * blockDim.x + threadIdx.x) * 4; i < n; i += stride) {
    float4 v = *(const float4*)(in + i);
    bf16x4 o = { (bf16)v.x, (bf16)v.y, (bf16)v.z, (bf16)v.w };
    *(bf16x4*)(out + i) = o;
  }
}

// ---------------- fused weight cast: wq|wk|wv -> wqkv, wo -> wob ----------------
__global__ void cast_w_kernel(const float* __restrict__ wq, const float* __restrict__ wk,
                              const float* __restrict__ wv, const float* __restrict__ wo,
                              bf16* __restrict__ wqkv, bf16* __restrict__ wob) {
  int stride = gridDim.x * blockDim.x;
  for (int g = blockIdx.x * blockDim.x + threadIdx.x; g < 2621440; g += stride) {
    const float* src; bf16* dst; int off;
    if (g < 1048576)      { src = wq; dst = wqkv;           off = g; }
    else if (g < 1310720) { src = wk; dst = wqkv + 4194304; off = g - 1048576; }
    else if (g < 1572864) { src = wv; dst = wqkv + 5242880; off = g - 1310720; }
    else                  { src = wo; dst = wob;            off = g - 1572864; }
    float4 v = *(const float4*)(src + (size_t)off * 4);
    bf16x4 o = { (bf16)v.x, (bf16)v.y, (bf16)v.z, (bf16)v.w };
    *(bf16x4*)(dst + (size_t)off * 4) = o;
  }
}

// ---------------- GEMM: C[m][n] = sum_k A[m][k] * W[n][k] ----------------
// BM=256 BN=128 BK=64, 512 thr (8 waves, 4M x 2N, 64x64/wave).
// 3-deep LDS ring (144KB), prefetch depth 2, counted vmcnt(6) at tile top
// (never drains to 0 in steady state - T4). XOR-swizzled LDS (T2) via
// pre-swizzled global source. 1 barrier/tile; setprio'd MFMA cluster (T5).
// Requires M == 4096 (bm = (wg&15)*256), N multiple of 128, K mult of 64.
template <typename OutT>
__global__ __launch_bounds__(512) void gemm256(const bf16* __restrict__ A,
                                               const bf16* __restrict__ W,
                                               OutT* __restrict__ C,
                                               int N, int K, int cpx) {
  constexpr int BM = 256, BN = 128, BK = 64;
  __shared__ __attribute__((aligned(16))) bf16 Ab[3][BM * BK];
  __shared__ __attribute__((aligned(16))) bf16 Bb[3][BN * BK];
  const int tid = threadIdx.x, lane = tid & 63, wave = tid >> 6;
  const int l15 = lane & 15, l4 = lane >> 4;
  const int orig = blockIdx.x;
  const int wg = (orig & 7) * cpx + (orig >> 3);   // XCD chunking (nwg % 8 == 0)
  const int bm = (wg & 15) * BM;                   // M/256 == 16
  const int bn = (wg >> 4) * BN;                   // bn-major
  const int wm = (wave >> 1) * 64, wn = (wave & 1) * 64;

  f32x4 acc[4][4] = {};

  const int NT = K / BK;
  // 6 global_load_lds per wave per stage (4 A + 2 B) -> vmcnt counts 6/stage
  auto stage = [&](int s, int k0) {
    #pragma unroll
    for (int i = 0; i < 4; ++i) {                  // A: 256x64 = 32KB
      int c = i * 512 + tid;
      int row = c >> 3;
      int gc = ((c & 7) ^ (row & 7)) << 3;
      __builtin_amdgcn_global_load_lds(
          (const __attribute__((address_space(1))) unsigned int*)(A + (size_t)(bm + row) * K + k0 + gc),
          (__attribute__((address_space(3))) unsigned int*)(&Ab[s][0] + c * 8), 16, 0, 0);
    }
    #pragma unroll
    for (int i = 0; i < 2; ++i) {                  // B: 128x64 = 16KB
      int c = i * 512 + tid;
      int row = c >> 3;
      int gc = ((c & 7) ^ (row & 7)) << 3;
      __builtin_amdgcn_global_load_lds(
          (const __attribute__((address_space(1))) unsigned int*)(W + (size_t)(bn + row) * K + k0 + gc),
          (__attribute__((address_space(3))) unsigned int*)(&Bb[s][0] + c * 8), 16, 0, 0);
    }
  };

  stage(0, 0);
  stage(1, BK);

  int d = 0;
  for (int t = 0; t < NT; ++t) {
    // tile top: newest stage (6 loads) may stay in flight; oldest must land.
    if (t + 1 < NT) { asm volatile("s_waitcnt vmcnt(6)" ::: "memory"); }
    else            { asm volatile("s_waitcnt vmcnt(0)" ::: "memory"); }
    __builtin_amdgcn_s_barrier();

    // read all 16 fragments of this tile
    bf16x8 af[2][4], bfr[2][4];
    #pragma unroll
    for (int kk = 0; kk < 2; ++kk) {
      #pragma unroll
      for (int mi = 0; mi < 4; ++mi) {
        int row = wm + mi * 16 + l15;
        af[kk][mi] = *(const bf16x8*)((const char*)&Ab[d][0] + row * 128 +
                                      (((kk * 4 + l4) ^ (row & 7)) << 4));
      }
      #pragma unroll
      for (int ni = 0; ni < 4; ++ni) {
        int row = wn + ni * 16 + l15;
        bfr[kk][ni] = *(const bf16x8*)((const char*)&Bb[d][0] + row * 128 +
                                       (((kk * 4 + l4) ^ (row & 7)) << 4));
      }
    }

    // prefetch tile t+2 into the ring slot freed by t-1
    if (t + 2 < NT) {
      int s = d + 2; if (s >= 3) s -= 3;
      stage(s, (t + 2) * BK);
    }

    __builtin_amdgcn_s_setprio(1);
    #pragma unroll
    for (int kk = 0; kk < 2; ++kk)
      #pragma unroll
      for (int mi = 0; mi < 4; ++mi)
        #pragma unroll
        for (int ni = 0; ni < 4; ++ni)
          acc[mi][ni] = __builtin_amdgcn_mfma_f32_16x16x32_bf16(af[kk][mi], bfr[kk][ni],
                                                                acc[mi][ni], 0, 0, 0);
    __builtin_amdgcn_s_setprio(0);

    ++d; if (d == 3) d = 0;
  }

  // ---- epilogue ----
  #pragma unroll
  for (int mi = 0; mi < 4; ++mi)
    #pragma unroll
    for (int ni = 0; ni < 4; ++ni) {
      size_t row = (size_t)bm + wm + mi * 16 + l4 * 4;
      int col = bn + wn + ni * 16 + l15;
      #pragma unroll
      for (int r = 0; r < 4; ++r)
        C[(row + r) * N + col] = (OutT)acc[mi][ni][r];
    }
}

// ---------------- RoPE, vectorized (unchanged) ----------------
__global__ void rope_kernel(bf16* __restrict__ qkv, const float* __restrict__ cs,
                            const float* __restrict__ sn) {
  int idx = blockIdx.x * blockDim.x + threadIdx.x;
  int m = idx / 160;
  int ch = idx - m * 160;
  int t = m & (T_SEQ - 1);
  int col, c;
  if (ch < 128) { int hh = ch >> 2; c = ch & 3; col = hh * 64 + c * 16; }
  else          { int ch2 = ch - 128; int hh = ch2 >> 2; c = ch2 & 3; col = DIM + hh * 64 + c * 16; }
  bf16* ptr = qkv + (size_t)m * QKV_N + col;
  bf16x8 v0 = *(bf16x8*)ptr, v1 = *(bf16x8*)(ptr + 8);
  const float* cp = cs + t * 32 + c * 8;
  const float* sp = sn + t * 32 + c * 8;
  float4 c0 = *(const float4*)cp, c1 = *(const float4*)(cp + 4);
  float4 s0 = *(const float4*)sp, s1 = *(const float4*)(sp + 4);
  float cc[8] = {c0.x, c0.y, c0.z, c0.w, c1.x, c1.y, c1.z, c1.w};
  float ss[8] = {s0.x, s0.y, s0.z, s0.w, s1.x, s1.y, s1.z, s1.w};
  bf16x8 o0, o1;
  #pragma unroll
  for (int j = 0; j < 4; ++j) {
    float a = (float)v0[2 * j], b = (float)v0[2 * j + 1];
    o0[2 * j]     = (bf16)(a * cc[j] - b * ss[j]);
    o0[2 * j + 1] = (bf16)(a * ss[j] + b * cc[j]);
  }
  #pragma unroll
  for (int j = 0; j < 4; ++j) {
    float a = (float)v1[2 * j], b = (float)v1[2 * j + 1];
    o1[2 * j]     = (bf16)(a * cc[4 + j] - b * ss[4 + j]);
    o1[2 * j + 1] = (bf16)(a * ss[4 + j] + b * cc[4 + j]);
  }
  *(bf16x8*)ptr = o0;
  *(bf16x8*)(ptr + 8) = o1;
}

// ---------------- Flash attention, causal GQA (unchanged from R10) ----------------
__global__ __launch_bounds__(512, 4) void attn_kernel(const bf16* __restrict__ qkv,
                                                      bf16* __restrict__ y) {
  const int h = blockIdx.x, b = blockIdx.z;
  const int strip = 15 - blockIdx.y;
  const int g = h >> 2;
  const int tid = threadIdx.x, lane = tid & 63, wave = tid >> 6;
  const int l15 = lane & 15, l4 = lane >> 4;
  const int qbase = strip * 128 + wave * 16;

  __shared__ __attribute__((aligned(16))) bf16 Kb[2][64 * 64];
  __shared__ __attribute__((aligned(16))) bf16 VTs[2][64 * 64];
  __shared__ __attribute__((aligned(16))) bf16 Pb[8][16 * 64];

  constexpr float SCALE2 = 0.125f * 1.44269504088896f;
  constexpr float THR_RAW = 8.0f / SCALE2;

  bf16x8 qf[2];
  {
    const bf16* qp = qkv + ((size_t)b * T_SEQ + qbase + l15) * QKV_N + h * HD + l4 * 8;
    qf[0] = *(const bf16x8*)(qp);
    qf[1] = *(const bf16x8*)(qp + 32);
  }

  f32x4 oacc[4] = {};
  float m_run = -INFINITY, l_run = 0.f;

  const int last_kt = (qbase + 15) >> 6;
  const int nt_loop = 2 * strip + 2;
  const size_t kvbase = (size_t)b * T_SEQ;

  {
    int r = tid >> 3;
    int csrc = ((tid & 7) << 3) ^ ((r & 7) << 3);
    __builtin_amdgcn_global_load_lds(
        (const __attribute__((address_space(1))) unsigned int*)
            (qkv + (kvbase + r) * QKV_N + DIM + g * HD + csrc),
        (__attribute__((address_space(3))) unsigned int*)(&Kb[0][0] + tid * 8), 16, 0, 0);
    const bf16* vp = qkv + (kvbase + wave * 8) * QKV_N + DIM + NKV * HD + g * HD + lane;
    bf16x8 vr;
    #pragma unroll
    for (int j = 0; j < 8; ++j) vr[j] = vp[(size_t)j * QKV_N];
    *(bf16x8*)((char*)&VTs[0][0] + ((lane * 128 + wave * 16) ^ ((lane & 7) << 4))) = vr;
    asm volatile("s_waitcnt vmcnt(0)" ::: "memory");
    __syncthreads();
  }

  int cur = 0;
  for (int kt = 0; kt < nt_loop; ++kt) {
    const bool has_next = (kt + 1) < nt_loop;
    bf16x8 vr;
    if (has_next) {
      int r = tid >> 3;
      int csrc = ((tid & 7) << 3) ^ ((r & 7) << 3);
      __builtin_amdgcn_global_load_lds(
          (const __attribute__((address_space(1))) unsigned int*)
              (qkv + (kvbase + (kt + 1) * 64 + r) * QKV_N + DIM + g * HD + csrc),
          (__attribute__((address_space(3))) unsigned int*)(&Kb[cur ^ 1][0] + tid * 8), 16, 0, 0);
      const bf16* vp = qkv + (kvbase + (kt + 1) * 64 + wave * 8) * QKV_N
                           + DIM + NKV * HD + g * HD + lane;
      #pragma unroll
      for (int j = 0; j < 8; ++j) vr[j] = vp[(size_t)j * QKV_N];
    }

    if (kt <= last_kt) {
      const bf16* kb = &Kb[cur][0];
      const bf16* vt = &VTs[cur][0];

      f32x4 z[4];
      #pragma unroll
      for (int nt = 0; nt < 4; ++nt) z[nt] = (f32x4){0.f, 0.f, 0.f, 0.f};
      #pragma unroll
      for (int nt = 0; nt < 4; ++nt)
        #pragma unroll
        for (int kk = 0; kk < 2; ++kk) {
          bf16x8 kf = *(const bf16x8*)((const char*)kb +
              (((nt * 16 + l15) * 128 + (kk * 32 + l4 * 8) * 2) ^ ((l15 & 7) << 4)));
          z[nt] = __builtin_amdgcn_mfma_f32_16x16x32_bf16(kf, qf[kk], z[nt], 0, 0, 0);
        }

      if (kt == last_kt) {
        const int qg = qbase + l15;
        #pragma unroll
        for (int nt = 0; nt < 4; ++nt)
          #pragma unroll
          for (int r = 0; r < 4; ++r)
            if (kt * 64 + nt * 16 + l4 * 4 + r > qg) z[nt][r] = -INFINITY;
      }

      float vm = z[0][0];
      #pragma unroll
      for (int nt = 0; nt < 4; ++nt)
        #pragma unroll
        for (int r = 0; r < 4; ++r) vm = fmaxf(vm, z[nt][r]);
      vm = fmaxf(vm, __shfl_xor(vm, 16));
      vm = fmaxf(vm, __shfl_xor(vm, 32));

      if (!__all(vm - m_run <= THR_RAW)) {
        float mnew = fmaxf(m_run, vm);
        float alpha = __builtin_amdgcn_exp2f((m_run - mnew) * SCALE2);
        l_run *= alpha;
        #pragma unroll
        for (int dt = 0; dt < 4; ++dt)
          #pragma unroll
          for (int r = 0; r < 4; ++r) oacc[dt][r] *= alpha;
        m_run = mnew;
      }
      const float ms = m_run * SCALE2;

      float ps = 0.f;
      #pragma unroll
      for (int nt = 0; nt < 4; ++nt)
        #pragma unroll
        for (int r = 0; r < 4; ++r) {
          float pv = __builtin_amdgcn_exp2f(__builtin_fmaf(z[nt][r], SCALE2, -ms));
          z[nt][r] = pv;
          ps += pv;
        }
      ps += __shfl_xor(ps, 16);
      ps += __shfl_xor(ps, 32);
      l_run += ps;

      bf16* pbw = &Pb[wave][0];
      #pragma unroll
      for (int nt = 0; nt < 4; ++nt) {
        bf16x4 pk = { (bf16)z[nt][0], (bf16)z[nt][1], (bf16)z[nt][2], (bf16)z[nt][3] };
        *(bf16x4*)((char*)pbw + ((l15 * 128 + nt * 32 + l4 * 8) ^ ((l15 & 7) << 4))) = pk;
      }

      #pragma unroll
      for (int kk = 0; kk < 2; ++kk) {
        bf16x8 pf = *(const bf16x8*)((const char*)pbw +
            ((l15 * 128 + kk * 64 + l4 * 16) ^ ((l15 & 7) << 4)));
        #pragma unroll
        for (int dt = 0; dt < 4; ++dt) {
          bf16x8 vf = *(const bf16x8*)((const char*)vt +
              (((dt * 16 + l15) * 128 + (kk * 32 + l4 * 8) * 2) ^ ((l15 & 7) << 4)));
          oacc[dt] = __builtin_amdgcn_mfma_f32_16x16x32_bf16(vf, pf, oacc[dt], 0, 0, 0);
        }
      }
    }

    if (has_next) {
      *(bf16x8*)((char*)&VTs[cur ^ 1][0] + ((lane * 128 + wave * 16) ^ ((lane & 7) << 4))) = vr;
      asm volatile("s_waitcnt vmcnt(0)" ::: "memory");
      __syncthreads();
      cur ^= 1;
    }
  }

  {
    float linv = __builtin_amdgcn_rcpf(l_run);
    bf16* yp = y + ((size_t)b * T_SEQ + qbase + l15) * DIM + h * HD + l4 * 4;
    #pragma unroll
    for (int dt = 0; dt < 4; ++dt) {
      bf16x4 ov = { (bf16)(oacc[dt][0] * linv), (bf16)(oacc[dt][1] * linv),
                    (bf16)(oacc[dt][2] * linv), (bf16)(oacc[dt][3] * linv) };
      *(bf16x4*)(yp + dt * 16) = ov;
    }
  }
}

// ---------------- launch ----------------
extern "C" void kernel_launch(void* const* d_in, const int* in_sizes, int n_in,
                              void* d_out, int out_size, void* d_ws, size_t ws_size,
                              hipStream_t stream) {
  const float* x    = (const float*)d_in[0];
  const float* cosb = (const float*)d_in[1];
  const float* sinb = (const float*)d_in[2];
  const float* wq   = (const float*)d_in[3];
  const float* wk   = (const float*)d_in[4];
  const float* wv   = (const float*)d_in[5];
  const float* wo   = (const float*)d_in[6];
  float* out = (float*)d_out;

  bf16* xb   = (bf16*)d_ws;                           // 4096*2048
  bf16* wqkv = xb + (size_t)MROWS * DIM;              // 3072*2048
  bf16* wob  = wqkv + (size_t)QKV_N * DIM;            // 2048*2048
  bf16* qkv  = wob + (size_t)DIM * DIM;               // 4096*3072
  bf16* y    = qkv + (size_t)MROWS * QKV_N;           // 4096*2048

  cast_kernel<<<2048, 256, 0, stream>>>(x, xb, MROWS * DIM);
  cast_w_kernel<<<2048, 256, 0, stream>>>(wq, wk, wv, wo, wqkv, wob);

  // QKV projection: M=4096, N=3072, K=2048 -> 384 blocks
  gemm256<bf16><<<384, 512, 0, stream>>>(xb, wqkv, qkv, QKV_N, DIM, 384 / 8);

  // RoPE on q,k
  rope_kernel<<<(MROWS * 160) / 256, 256, 0, stream>>>(qkv, cosb, sinb);

  // attention: one 128-row strip per 512-thr block (8 waves x 16 rows)
  attn_kernel<<<dim3(NH, 16, 2), 512, 0, stream>>>(qkv, y);

  // output projection: M=4096, N=2048, K=2048 -> 256 blocks
  gemm256<float><<<256, 512, 0, stream>>>(y, wob, out, DIM, DIM, 256 / 8);
}